// Round 1
// 2125.329 us; speedup vs baseline: 1.0583x; 1.0583x over previous
//
#include <hip/hip_runtime.h>
#include <hip/hip_bf16.h>
#include <math.h>

#define TOK    4096   // B*S
#define HS     2048
#define CONVD  8192
#define KEYD   2048
#define VALD   4096
#define NKH    16
#define NVH    32
#define DKH    128
#define DVH    128
#define SEQ    2048
#define NBATCH 2
#define EPSF   1e-6f

typedef __attribute__((ext_vector_type(8))) short short8;
typedef __attribute__((ext_vector_type(4))) float floatx4;

static __device__ __forceinline__ unsigned short f2bf(float x) {
  union { float f; unsigned u; } c; c.f = x;
  unsigned r = (c.u + 0x7FFF + ((c.u >> 16) & 1)) >> 16;
  return (unsigned short)r;
}

// ---------------- fp32 GEMM (tiny ba projection only) ----------------
__global__ __launch_bounds__(256) void gemm_nt(
    const float* __restrict__ A, const float* __restrict__ B,
    float* __restrict__ C, int M, int N, int K) {
  __shared__ float As[16][68];
  __shared__ float Bs[16][68];
  const int tx = threadIdx.x & 15;
  const int ty = threadIdx.x >> 4;
  const int row0 = blockIdx.y * 64;
  const int col0 = blockIdx.x * 64;
  const int lr = threadIdx.x >> 2;
  const int lc = (threadIdx.x & 3) * 4;
  float acc[4][4] = {};
  for (int k0 = 0; k0 < K; k0 += 16) {
    float4 av = *(const float4*)&A[(size_t)(row0 + lr) * K + (k0 + lc)];
    float4 bv = *(const float4*)&B[(size_t)(col0 + lr) * K + (k0 + lc)];
    As[lc + 0][lr] = av.x; As[lc + 1][lr] = av.y;
    As[lc + 2][lr] = av.z; As[lc + 3][lr] = av.w;
    Bs[lc + 0][lr] = bv.x; Bs[lc + 1][lr] = bv.y;
    Bs[lc + 2][lr] = bv.z; Bs[lc + 3][lr] = bv.w;
    __syncthreads();
    #pragma unroll
    for (int kk = 0; kk < 16; kk++) {
      float a[4], b[4];
      #pragma unroll
      for (int i = 0; i < 4; i++) a[i] = As[kk][ty * 4 + i];
      #pragma unroll
      for (int i = 0; i < 4; i++) b[i] = Bs[kk][tx * 4 + i];
      #pragma unroll
      for (int i = 0; i < 4; i++)
        #pragma unroll
        for (int j = 0; j < 4; j++)
          acc[i][j] += a[i] * b[j];
    }
    __syncthreads();
  }
  #pragma unroll
  for (int i = 0; i < 4; i++) {
    float4 v = make_float4(acc[i][0], acc[i][1], acc[i][2], acc[i][3]);
    *(float4*)&C[(size_t)(row0 + ty * 4 + i) * N + (col0 + tx * 4)] = v;
  }
}

// ---------------- fp32 -> bf16 cast ----------------
__global__ __launch_bounds__(256) void cast_bf16(
    const float4* __restrict__ src, ushort4* __restrict__ dst, int n4) {
  int i = blockIdx.x * 256 + threadIdx.x;
  if (i < n4) {
    float4 v = src[i];
    ushort4 o;
    o.x = f2bf(v.x); o.y = f2bf(v.y); o.z = f2bf(v.z); o.w = f2bf(v.w);
    dst[i] = o;
  }
}

// ---------------- bf16 MFMA GEMM: C[M,N] = A[M,K] * B[N,K]^T ----------------
__global__ __launch_bounds__(256) void gemm_bf16_nt(
    const ushort* __restrict__ A, const ushort* __restrict__ B,
    float* __restrict__ C, int M, int N, int K) {
  __shared__ ushort Asm[128 * 32];
  __shared__ ushort Bsm[128 * 32];
  const int tid = threadIdx.x;
  const int w = tid >> 6, l = tid & 63;
  const int row0 = blockIdx.y * 128, col0 = blockIdx.x * 128;
  const int wm = w >> 1, wn = w & 1;

  floatx4 acc[4][4];
  #pragma unroll
  for (int i = 0; i < 4; i++)
    #pragma unroll
    for (int j = 0; j < 4; j++)
      acc[i][j] = (floatx4){0.f, 0.f, 0.f, 0.f};

  const int srow = w * 16 + (l >> 2);
  const int scol = (l & 3) * 8;
  const ushort* Ag = A + (size_t)(row0 + srow) * K + scol;
  const ushort* Bg = B + (size_t)(col0 + srow) * K + scol;

  for (int k0 = 0; k0 < K; k0 += 32) {
    #pragma unroll
    for (int c = 0; c < 2; c++) {
      __builtin_amdgcn_global_load_lds(
          (const __attribute__((address_space(1))) void*)(Ag + (size_t)(c * 64) * K + k0),
          (__attribute__((address_space(3))) void*)&Asm[(c * 64 + w * 16) * 32],
          16, 0, 0);
      __builtin_amdgcn_global_load_lds(
          (const __attribute__((address_space(1))) void*)(Bg + (size_t)(c * 64) * K + k0),
          (__attribute__((address_space(3))) void*)&Bsm[(c * 64 + w * 16) * 32],
          16, 0, 0);
    }
    __syncthreads();
    short8 af[4], bfv[4];
    #pragma unroll
    for (int i = 0; i < 4; i++) {
      af[i]  = *(const short8*)&Asm[(wm * 64 + i * 16 + (l & 15)) * 32 + (l >> 4) * 8];
      bfv[i] = *(const short8*)&Bsm[(wn * 64 + i * 16 + (l & 15)) * 32 + (l >> 4) * 8];
    }
    #pragma unroll
    for (int i = 0; i < 4; i++)
      #pragma unroll
      for (int j = 0; j < 4; j++)
        acc[i][j] = __builtin_amdgcn_mfma_f32_16x16x32_bf16(af[i], bfv[j], acc[i][j], 0, 0, 0);
    __syncthreads();
  }

  const int cl = l & 15, rq = l >> 4;
  #pragma unroll
  for (int i = 0; i < 4; i++) {
    int r0 = row0 + wm * 64 + i * 16 + rq * 4;
    #pragma unroll
    for (int j = 0; j < 4; j++) {
      int cc = col0 + wn * 64 + j * 16 + cl;
      #pragma unroll
      for (int r = 0; r < 4; r++)
        C[(size_t)(r0 + r) * N + cc] = acc[i][j][r];
    }
  }
}

// ------------- causal depthwise conv (K=4) + SiLU -------------
__global__ __launch_bounds__(256) void conv_silu(
    const float* __restrict__ qkv, const float* __restrict__ cw,
    float* __restrict__ mix) {
  size_t idx = (size_t)blockIdx.x * 256 + threadIdx.x;
  int c = (int)(idx % CONVD);
  size_t t = idx / CONVD;
  int s = (int)(t % SEQ);
  float w0 = cw[c * 4 + 0], w1 = cw[c * 4 + 1], w2 = cw[c * 4 + 2], w3 = cw[c * 4 + 3];
  const float* col = qkv + t * CONVD + c;
  float acc = w3 * col[0];
  if (s >= 1) acc += w2 * col[-(ptrdiff_t)CONVD];
  if (s >= 2) acc += w1 * col[-2 * (ptrdiff_t)CONVD];
  if (s >= 3) acc += w0 * col[-3 * (ptrdiff_t)CONVD];
  float sig = 1.f / (1.f + expf(-acc));
  mix[t * CONVD + c] = acc * sig;
}

// ------------- gates: write float2 {ge, beta} per (t, h) -------------
__global__ __launch_bounds__(256) void gates_kernel(
    const float* __restrict__ ba, const float* __restrict__ A_log,
    const float* __restrict__ dt_bias, float2* __restrict__ g2) {
  int idx = blockIdx.x * 256 + threadIdx.x;
  int h = idx & 31;
  size_t t = (size_t)(idx >> 5);
  float bv = ba[t * 64 + h];
  float av = ba[t * 64 + 32 + h];
  float beta = 1.f / (1.f + expf(-bv));
  float xx = av + dt_bias[h];
  float sp = (xx > 20.f) ? xx : log1pf(expf(xx));
  float ge = expf(-expf(A_log[h]) * sp);
  g2[t * 32 + h] = make_float2(ge, beta);
}

// ------------- per-head L2 norm of q and k (in place in mix) -------------
__global__ __launch_bounds__(256) void l2norm_qk(float* __restrict__ mix) {
  int wid = (blockIdx.x * 256 + threadIdx.x) >> 6;
  int lane = threadIdx.x & 63;
  size_t t = (size_t)(wid >> 5);
  int hh = wid & 31;
  float* p = mix + t * CONVD + (size_t)hh * DKH;
  float v0 = p[lane], v1 = p[lane + 64];
  float ss = v0 * v0 + v1 * v1;
  #pragma unroll
  for (int off = 32; off >= 1; off >>= 1) ss += __shfl_xor(ss, off, 64);
  float sc = rsqrtf(ss + EPSF);
  p[lane] = v0 * sc;
  p[lane + 64] = v1 * sc;
}

// ------------- sequential delta-rule scan v4 -------------
// grid: 1024 = vc(16) x b(2) x h(32); 64 threads; lane = kseg(8)*8 + vs(8)
// per-lane state: 16 k x 1 v (kseg -> 16 k rows, vs -> 1 v col of an 8-col slice).
// One-step lookahead: carry pp_{t} = k_t . st_{t-1} (reduced). Per step:
//   delta_t   = be_t * (v_t - ge_t * pp_t)               (known at step START)
//   e_partial = ge_t*(k_{t+1}.st_{t-1}) + (k_{t+1}.k_t)*delta_t   [linear in delta]
//   pp_{t+1}  = butterfly_sum(e_partial)   <- single reduced value per step
//   st        = ge_t*st + k_t*delta ; o_t = q_t.st (reduced, kseg0 stores)
// Inter-step serial chain is delta -> 1 FMA -> delta; reductions pipeline
// under the issue window. Ring-4 register prefetch, ~180 VGPR (no AGPR parking).
struct Frag2 { float4 k[4]; float4 q[4]; float v; float2 g; };

__device__ __forceinline__ void load_frag2(
    Frag2& f, const float* __restrict__ kp, const float* __restrict__ qp,
    const float* __restrict__ vp, const float2* __restrict__ gp, int s) {
  size_t off = (size_t)s * CONVD;
  #pragma unroll
  for (int m = 0; m < 4; m++) {
    f.k[m] = *(const float4*)(kp + off + m * 4);
    f.q[m] = *(const float4*)(qp + off + m * 4);
  }
  f.v = vp[off];
  f.g = gp[(size_t)s * 32];
}

__device__ __forceinline__ void scan_step2(
    const Frag2& fc, const Frag2& fn, float* st, float& pp,
    float* __restrict__ orow, int s, int outl) {
  const float* kc = (const float*)&fc.k[0];
  const float* kn = (const float*)&fn.k[0];
  const float* qc = (const float*)&fc.q[0];
  const float ge = fc.g.x, be = fc.g.y;
  const float delta = be * (fc.v - ge * pp);
  // lookahead: c = k_{t+1}.st_old, d = k_{t+1}.k_t  (read st BEFORE update)
  float c0 = 0.f, c1 = 0.f, d0 = 0.f, d1 = 0.f;
  #pragma unroll
  for (int j = 0; j < 8; j++) {
    c0 += kn[j]     * st[j];
    c1 += kn[8 + j] * st[8 + j];
    d0 += kn[j]     * kc[j];
    d1 += kn[8 + j] * kc[8 + j];
  }
  float e = ge * (c0 + c1) + (d0 + d1) * delta;
  e += __shfl_xor(e, 8, 64);
  e += __shfl_xor(e, 16, 64);
  e += __shfl_xor(e, 32, 64);
  // state update + output dot (overlaps with e's shuffle latency)
  float o0 = 0.f, o1 = 0.f;
  #pragma unroll
  for (int j = 0; j < 8; j++) {
    st[j]     = ge * st[j]     + kc[j] * delta;     o0 += qc[j]     * st[j];
    st[8 + j] = ge * st[8 + j] + kc[8 + j] * delta; o1 += qc[8 + j] * st[8 + j];
  }
  float op = o0 + o1;
  op += __shfl_xor(op, 8, 64);
  op += __shfl_xor(op, 16, 64);
  op += __shfl_xor(op, 32, 64);
  pp = e;
  if (outl) orow[(size_t)s * VALD] = op;
}

__global__ __launch_bounds__(64, 1) void scan_kernel(
    const float* __restrict__ mix, const float* __restrict__ gate2,
    float* __restrict__ core) {
  const int blk = blockIdx.x;
  // vc-siblings (which share q/k rows) are stride-64 in blockIdx -> same XCD L2
  const int chain = blk & 63;
  const int vc = blk >> 6;          // [0,16)
  const int h = chain & 31;
  const int b = chain >> 5;
  const int lane = threadIdx.x;
  const int kseg = lane >> 3;       // [0,8): 16 k rows each
  const int vs = lane & 7;          // [0,8): 1 v col each
  const int kh = h >> 1;

  const float* qp = mix + (size_t)b * SEQ * CONVD + (size_t)kh * DKH + kseg * 16;
  const float* kp = qp + KEYD;
  const float* vp = mix + (size_t)b * SEQ * CONVD + 2 * KEYD + (size_t)h * DVH + vc * 8 + vs;
  const float2* gp = (const float2*)(gate2) + (size_t)b * SEQ * 32 + h;
  float* orow = core + (size_t)b * SEQ * VALD + (size_t)h * DVH + vc * 8 + vs;
  const int outl = (kseg == 0);

  float st[16];
  #pragma unroll
  for (int i = 0; i < 16; i++) st[i] = 0.f;

  Frag2 F0, F1, F2, F3;
  load_frag2(F0, kp, qp, vp, gp, 0);
  load_frag2(F1, kp, qp, vp, gp, 1);
  load_frag2(F2, kp, qp, vp, gp, 2);
  load_frag2(F3, kp, qp, vp, gp, 3);

  float pp = 0.f;   // pp_0 = k_0 . st_{-1} = 0

  int s = 0;
  for (; s < SEQ - 4; s += 4) {
    scan_step2(F0, F1, st, pp, orow, s, outl);
    __builtin_amdgcn_sched_barrier(0);
    load_frag2(F0, kp, qp, vp, gp, s + 4);
    __builtin_amdgcn_sched_barrier(0);
    scan_step2(F1, F2, st, pp, orow, s + 1, outl);
    __builtin_amdgcn_sched_barrier(0);
    load_frag2(F1, kp, qp, vp, gp, s + 5);
    __builtin_amdgcn_sched_barrier(0);
    scan_step2(F2, F3, st, pp, orow, s + 2, outl);
    __builtin_amdgcn_sched_barrier(0);
    load_frag2(F2, kp, qp, vp, gp, s + 6);
    __builtin_amdgcn_sched_barrier(0);
    scan_step2(F3, F0, st, pp, orow, s + 3, outl);
    __builtin_amdgcn_sched_barrier(0);
    load_frag2(F3, kp, qp, vp, gp, s + 7);
    __builtin_amdgcn_sched_barrier(0);
  }
  // epilogue: steps SEQ-4 .. SEQ-1 (all frags already loaded).
  // Final step's fn (F0) holds stale-but-finite data; its pp result is unused.
  scan_step2(F0, F1, st, pp, orow, SEQ - 4, outl);
  scan_step2(F1, F2, st, pp, orow, SEQ - 3, outl);
  scan_step2(F2, F3, st, pp, orow, SEQ - 2, outl);
  scan_step2(F3, F0, st, pp, orow, SEQ - 1, outl);
}

// ------------- RMSNorm(1+w) * silu(z) -> bf16 -------------
__global__ __launch_bounds__(256) void rmsnorm_silu(
    const float* __restrict__ core, const float* __restrict__ zbuf,
    const float* __restrict__ norm_w, ushort* __restrict__ out_bf) {
  int t = blockIdx.x;
  int tid = threadIdx.x;
  const float* row = core + (size_t)t * VALD;
  const float* zrow = zbuf + (size_t)t * VALD;
  ushort* orow = out_bf + (size_t)t * VALD;
  float vals[16];
  float ss = 0.f;
  #pragma unroll
  for (int i = 0; i < 16; i++) { float x = row[tid + i * 256]; vals[i] = x; ss += x * x; }
  #pragma unroll
  for (int off = 32; off >= 1; off >>= 1) ss += __shfl_xor(ss, off, 64);
  __shared__ float red[4];
  if ((tid & 63) == 0) red[tid >> 6] = ss;
  __syncthreads();
  float tot = red[0] + red[1] + red[2] + red[3];
  float scale = rsqrtf(tot * (1.f / VALD) + EPSF);
  #pragma unroll
  for (int i = 0; i < 16; i++) {
    int c = tid + i * 256;
    float z = zrow[c];
    float sz = z / (1.f + expf(-z));
    orow[c] = f2bf(vals[i] * scale * (1.f + norm_w[c]) * sz);
  }
}

extern "C" void kernel_launch(void* const* d_in, const int* in_sizes, int n_in,
                              void* d_out, int out_size, void* d_ws, size_t ws_size,
                              hipStream_t stream) {
  const float* x       = (const float*)d_in[0];
  const float* W_qkvz  = (const float*)d_in[1];
  const float* W_ba    = (const float*)d_in[2];
  const float* conv_w  = (const float*)d_in[3];
  const float* dt_bias = (const float*)d_in[4];
  const float* A_log   = (const float*)d_in[5];
  const float* norm_w  = (const float*)d_in[6];
  const float* W_out   = (const float*)d_in[7];
  float* out = (float*)d_out;

  // workspace layout (floats), total 84,410,368 fl = 337.6 MB
  float* ws = (float*)d_ws;
  float* A  = ws;                         // 33,554,432 fl
  float* Bp = A + (size_t)33554432;       // 33,554,432 fl
  float* Cp = Bp + (size_t)33554432;      // 16,777,216 fl
  float* ba = Cp + (size_t)16777216;      //    262,144 fl
  float* g2 = ba + (size_t)262144;        //    262,144 fl (float2[TOK*32])

  ushort* x_bf    = (ushort*)Cp;
  ushort* Wqkv_bf = (ushort*)Bp;
  float*  zb      = A;
  ushort* core_bf = (ushort*)(A + (size_t)16777216);
  ushort* Wz_bf   = (ushort*)(A + (size_t)25165824);
  ushort* Wo_bf   = (ushort*)Bp;
  float*  mix     = Bp;
  float*  core    = Cp;

  // 1) casts for qkv projection
  cast_bf16<<<(TOK * HS / 4 + 255) / 256, 256, 0, stream>>>((const float4*)x, (ushort4*)x_bf, TOK * HS / 4);
  cast_bf16<<<(CONVD * HS / 4 + 255) / 256, 256, 0, stream>>>((const float4*)W_qkvz, (ushort4*)Wqkv_bf, CONVD * HS / 4);
  // 2) qkv projection (bf16 MFMA): [TOK, 8192]
  gemm_bf16_nt<<<dim3(CONVD / 128, TOK / 128), 256, 0, stream>>>(x_bf, Wqkv_bf, A, TOK, CONVD, HS);
  // 3) ba projection (fp32, tiny)
  gemm_nt<<<dim3(1, TOK / 64), 256, 0, stream>>>(x, W_ba, ba, TOK, 64, HS);
  // 4) conv + silu: A -> mix (frees A, overwrites Wqkv_bf in Bp)
  conv_silu<<<(int)(((size_t)TOK * CONVD) / 256), 256, 0, stream>>>(A, conv_w, mix);
  // 5) z projection: cast z-rows of W_qkvz, GEMM into A
  cast_bf16<<<(VALD * HS / 4 + 255) / 256, 256, 0, stream>>>(
      (const float4*)(W_qkvz + (size_t)(2 * KEYD + VALD) * HS), (ushort4*)Wz_bf, VALD * HS / 4);
  gemm_bf16_nt<<<dim3(VALD / 128, TOK / 128), 256, 0, stream>>>(x_bf, Wz_bf, zb, TOK, VALD, HS);
  // 6) gates -> float2 buffer
  gates_kernel<<<TOK * NVH / 256, 256, 0, stream>>>(ba, A_log, dt_bias, (float2*)g2);
  // 7) l2 norm q,k (in place in mix)
  l2norm_qk<<<TOK * 32 / 4, 256, 0, stream>>>(mix);
  // 8) scan v4: finer split (16 vc), lookahead recurrence, ring-4 prefetch
  scan_kernel<<<NBATCH * NVH * 16, 64, 0, stream>>>(mix, g2, core);
  // 9) rmsnorm * silu(z) -> bf16
  rmsnorm_silu<<<TOK, 256, 0, stream>>>(core, zb, norm_w, core_bf);
  // 10) output projection
  cast_bf16<<<(HS * VALD / 4 + 255) / 256, 256, 0, stream>>>((const float4*)W_out, (ushort4*)Wo_bf, HS * VALD / 4);
  gemm_bf16_nt<<<dim3(HS / 128, TOK / 128), 256, 0, stream>>>(core_bf, Wo_bf, out, TOK, HS, VALD);
}

// Round 2
// 1884.701 us; speedup vs baseline: 1.1934x; 1.1277x over previous
//
#include <hip/hip_runtime.h>
#include <hip/hip_bf16.h>
#include <math.h>

#define TOK    4096   // B*S
#define HS     2048
#define CONVD  8192
#define KEYD   2048
#define VALD   4096
#define NKH    16
#define NVH    32
#define DKH    128
#define DVH    128
#define SEQ    2048
#define NBATCH 2
#define EPSF   1e-6f

typedef __attribute__((ext_vector_type(8))) short short8;
typedef __attribute__((ext_vector_type(4))) float floatx4;
typedef __attribute__((ext_vector_type(2))) unsigned int uint2v;

static __device__ __forceinline__ unsigned short f2bf(float x) {
  union { float f; unsigned u; } c; c.f = x;
  unsigned r = (c.u + 0x7FFF + ((c.u >> 16) & 1)) >> 16;
  return (unsigned short)r;
}

// ---------------- fp32 GEMM (tiny ba projection only) ----------------
__global__ __launch_bounds__(256) void gemm_nt(
    const float* __restrict__ A, const float* __restrict__ B,
    float* __restrict__ C, int M, int N, int K) {
  __shared__ float As[16][68];
  __shared__ float Bs[16][68];
  const int tx = threadIdx.x & 15;
  const int ty = threadIdx.x >> 4;
  const int row0 = blockIdx.y * 64;
  const int col0 = blockIdx.x * 64;
  const int lr = threadIdx.x >> 2;
  const int lc = (threadIdx.x & 3) * 4;
  float acc[4][4] = {};
  for (int k0 = 0; k0 < K; k0 += 16) {
    float4 av = *(const float4*)&A[(size_t)(row0 + lr) * K + (k0 + lc)];
    float4 bv = *(const float4*)&B[(size_t)(col0 + lr) * K + (k0 + lc)];
    As[lc + 0][lr] = av.x; As[lc + 1][lr] = av.y;
    As[lc + 2][lr] = av.z; As[lc + 3][lr] = av.w;
    Bs[lc + 0][lr] = bv.x; Bs[lc + 1][lr] = bv.y;
    Bs[lc + 2][lr] = bv.z; Bs[lc + 3][lr] = bv.w;
    __syncthreads();
    #pragma unroll
    for (int kk = 0; kk < 16; kk++) {
      float a[4], b[4];
      #pragma unroll
      for (int i = 0; i < 4; i++) a[i] = As[kk][ty * 4 + i];
      #pragma unroll
      for (int i = 0; i < 4; i++) b[i] = Bs[kk][tx * 4 + i];
      #pragma unroll
      for (int i = 0; i < 4; i++)
        #pragma unroll
        for (int j = 0; j < 4; j++)
          acc[i][j] += a[i] * b[j];
    }
    __syncthreads();
  }
  #pragma unroll
  for (int i = 0; i < 4; i++) {
    float4 v = make_float4(acc[i][0], acc[i][1], acc[i][2], acc[i][3]);
    *(float4*)&C[(size_t)(row0 + ty * 4 + i) * N + (col0 + tx * 4)] = v;
  }
}

// ---------------- fp32 -> bf16 cast ----------------
__global__ __launch_bounds__(256) void cast_bf16(
    const float4* __restrict__ src, ushort4* __restrict__ dst, int n4) {
  int i = blockIdx.x * 256 + threadIdx.x;
  if (i < n4) {
    float4 v = src[i];
    ushort4 o;
    o.x = f2bf(v.x); o.y = f2bf(v.y); o.z = f2bf(v.z); o.w = f2bf(v.w);
    dst[i] = o;
  }
}

// ---------------- bf16 MFMA GEMM: C[M,N] = A[M,K] * B[N,K]^T ----------------
__global__ __launch_bounds__(256) void gemm_bf16_nt(
    const ushort* __restrict__ A, const ushort* __restrict__ B,
    float* __restrict__ C, int M, int N, int K) {
  __shared__ ushort Asm[128 * 32];
  __shared__ ushort Bsm[128 * 32];
  const int tid = threadIdx.x;
  const int w = tid >> 6, l = tid & 63;
  const int row0 = blockIdx.y * 128, col0 = blockIdx.x * 128;
  const int wm = w >> 1, wn = w & 1;

  floatx4 acc[4][4];
  #pragma unroll
  for (int i = 0; i < 4; i++)
    #pragma unroll
    for (int j = 0; j < 4; j++)
      acc[i][j] = (floatx4){0.f, 0.f, 0.f, 0.f};

  const int srow = w * 16 + (l >> 2);
  const int scol = (l & 3) * 8;
  const ushort* Ag = A + (size_t)(row0 + srow) * K + scol;
  const ushort* Bg = B + (size_t)(col0 + srow) * K + scol;

  for (int k0 = 0; k0 < K; k0 += 32) {
    #pragma unroll
    for (int c = 0; c < 2; c++) {
      __builtin_amdgcn_global_load_lds(
          (const __attribute__((address_space(1))) void*)(Ag + (size_t)(c * 64) * K + k0),
          (__attribute__((address_space(3))) void*)&Asm[(c * 64 + w * 16) * 32],
          16, 0, 0);
      __builtin_amdgcn_global_load_lds(
          (const __attribute__((address_space(1))) void*)(Bg + (size_t)(c * 64) * K + k0),
          (__attribute__((address_space(3))) void*)&Bsm[(c * 64 + w * 16) * 32],
          16, 0, 0);
    }
    __syncthreads();
    short8 af[4], bfv[4];
    #pragma unroll
    for (int i = 0; i < 4; i++) {
      af[i]  = *(const short8*)&Asm[(wm * 64 + i * 16 + (l & 15)) * 32 + (l >> 4) * 8];
      bfv[i] = *(const short8*)&Bsm[(wn * 64 + i * 16 + (l & 15)) * 32 + (l >> 4) * 8];
    }
    #pragma unroll
    for (int i = 0; i < 4; i++)
      #pragma unroll
      for (int j = 0; j < 4; j++)
        acc[i][j] = __builtin_amdgcn_mfma_f32_16x16x32_bf16(af[i], bfv[j], acc[i][j], 0, 0, 0);
    __syncthreads();
  }

  const int cl = l & 15, rq = l >> 4;
  #pragma unroll
  for (int i = 0; i < 4; i++) {
    int r0 = row0 + wm * 64 + i * 16 + rq * 4;
    #pragma unroll
    for (int j = 0; j < 4; j++) {
      int cc = col0 + wn * 64 + j * 16 + cl;
      #pragma unroll
      for (int r = 0; r < 4; r++)
        C[(size_t)(r0 + r) * N + cc] = acc[i][j][r];
    }
  }
}

// ------------- causal depthwise conv (K=4) + SiLU -------------
__global__ __launch_bounds__(256) void conv_silu(
    const float* __restrict__ qkv, const float* __restrict__ cw,
    float* __restrict__ mix) {
  size_t idx = (size_t)blockIdx.x * 256 + threadIdx.x;
  int c = (int)(idx % CONVD);
  size_t t = idx / CONVD;
  int s = (int)(t % SEQ);
  float w0 = cw[c * 4 + 0], w1 = cw[c * 4 + 1], w2 = cw[c * 4 + 2], w3 = cw[c * 4 + 3];
  const float* col = qkv + t * CONVD + c;
  float acc = w3 * col[0];
  if (s >= 1) acc += w2 * col[-(ptrdiff_t)CONVD];
  if (s >= 2) acc += w1 * col[-2 * (ptrdiff_t)CONVD];
  if (s >= 3) acc += w0 * col[-3 * (ptrdiff_t)CONVD];
  float sig = 1.f / (1.f + expf(-acc));
  mix[t * CONVD + c] = acc * sig;
}

// ------------- gates: write float2 {ge, beta} per (t, h) -------------
__global__ __launch_bounds__(256) void gates_kernel(
    const float* __restrict__ ba, const float* __restrict__ A_log,
    const float* __restrict__ dt_bias, float2* __restrict__ g2) {
  int idx = blockIdx.x * 256 + threadIdx.x;
  int h = idx & 31;
  size_t t = (size_t)(idx >> 5);
  float bv = ba[t * 64 + h];
  float av = ba[t * 64 + 32 + h];
  float beta = 1.f / (1.f + expf(-bv));
  float xx = av + dt_bias[h];
  float sp = (xx > 20.f) ? xx : log1pf(expf(xx));
  float ge = expf(-expf(A_log[h]) * sp);
  g2[t * 32 + h] = make_float2(ge, beta);
}

// ------------- per-head L2 norm of q and k (in place in mix) -------------
__global__ __launch_bounds__(256) void l2norm_qk(float* __restrict__ mix) {
  int wid = (blockIdx.x * 256 + threadIdx.x) >> 6;
  int lane = threadIdx.x & 63;
  size_t t = (size_t)(wid >> 5);
  int hh = wid & 31;
  float* p = mix + t * CONVD + (size_t)hh * DKH;
  float v0 = p[lane], v1 = p[lane + 64];
  float ss = v0 * v0 + v1 * v1;
  #pragma unroll
  for (int off = 32; off >= 1; off >>= 1) ss += __shfl_xor(ss, off, 64);
  float sc = rsqrtf(ss + EPSF);
  p[lane] = v0 * sc;
  p[lane + 64] = v1 * sc;
}

// ------------- sequential delta-rule scan v5 -------------
// grid: 1024 = vc(16) x b(2) x h(32); 64 threads; lane = kseg(8)*8 + vs(8)
// per-lane state: 16 k x 1 v.
// v5: the kseg butterfly reduction (lanes ^8, ^16, ^32) is done ENTIRELY in
// VALU: DPP row_ror:8 (lane^8 within a 16-lane row), v_permlane16_swap_b32
// (row-pair sum = lane^16), v_permlane32_swap_b32 (half swap = lane^32).
// No DS-pipe ops -> no ~120cy lgkmcnt serialization (v4's dominant stall).
// With reductions cheap, the lookahead recurrence is dropped (saves the
// kn.kc correction dot, 16 FMA/lane/step). Ring-4 register prefetch kept.
struct Frag2 { float4 k[4]; float4 q[4]; float v; float2 g; };

__device__ __forceinline__ void load_frag2(
    Frag2& f, const float* __restrict__ kp, const float* __restrict__ qp,
    const float* __restrict__ vp, const float2* __restrict__ gp, int s) {
  size_t off = (size_t)s * CONVD;
  #pragma unroll
  for (int m = 0; m < 4; m++) {
    f.k[m] = *(const float4*)(kp + off + m * 4);
    f.q[m] = *(const float4*)(qp + off + m * 4);
  }
  f.v = vp[off];
  f.g = gp[(size_t)s * 32];
}

// sum over the 8 kseg groups (lanes differing in bits 3,4,5) — all VALU.
static __device__ __forceinline__ float red_kseg(float x) {
  // stage 1: lane ^ 8 via DPP row_ror:8 (0x128)
  int xi = __builtin_bit_cast(int, x);
  int r8 = __builtin_amdgcn_update_dpp(0, xi, 0x128, 0xf, 0xf, false);
  x += __builtin_bit_cast(float, r8);
  // stage 2: lane ^ 16 via v_permlane16_swap_b32
#if __has_builtin(__builtin_amdgcn_permlane16_swap)
  {
    unsigned u = (unsigned)__builtin_bit_cast(int, x);
    uint2v r = __builtin_amdgcn_permlane16_swap(u, u, false, false);
    x = __builtin_bit_cast(float, (int)r.x) + __builtin_bit_cast(float, (int)r.y);
  }
#else
  x += __shfl_xor(x, 16, 64);
#endif
  // stage 3: lane ^ 32 via v_permlane32_swap_b32
#if __has_builtin(__builtin_amdgcn_permlane32_swap)
  {
    unsigned u = (unsigned)__builtin_bit_cast(int, x);
    uint2v r = __builtin_amdgcn_permlane32_swap(u, u, false, false);
    x = __builtin_bit_cast(float, (int)r.x) + __builtin_bit_cast(float, (int)r.y);
  }
#else
  x += __shfl_xor(x, 32, 64);
#endif
  return x;
}

__device__ __forceinline__ void scan_step(
    const Frag2& f, float* st, float* __restrict__ orow, int s, int outl) {
  const float* kc = (const float*)&f.k[0];
  const float* qc = (const float*)&f.q[0];
  const float ge = f.g.x, be = f.g.y;
  // pp = k_t . st_{t-1}
  float a0 = 0.f, a1 = 0.f;
  #pragma unroll
  for (int j = 0; j < 8; j++) {
    a0 += kc[j]     * st[j];
    a1 += kc[8 + j] * st[8 + j];
  }
  float pp = red_kseg(a0 + a1);
  const float delta = be * (f.v - ge * pp);
  // state update + output dot
  float o0 = 0.f, o1 = 0.f;
  #pragma unroll
  for (int j = 0; j < 8; j++) {
    st[j]     = ge * st[j]     + kc[j] * delta;     o0 += qc[j]     * st[j];
    st[8 + j] = ge * st[8 + j] + kc[8 + j] * delta; o1 += qc[8 + j] * st[8 + j];
  }
  float op = red_kseg(o0 + o1);
  if (outl) orow[(size_t)s * VALD] = op;
}

__global__ __launch_bounds__(64, 1) void scan_kernel(
    const float* __restrict__ mix, const float* __restrict__ gate2,
    float* __restrict__ core) {
  const int blk = blockIdx.x;
  // vc-siblings (which share q/k rows) are stride-64 in blockIdx -> same XCD L2
  const int chain = blk & 63;
  const int vc = blk >> 6;          // [0,16)
  const int h = chain & 31;
  const int b = chain >> 5;
  const int lane = threadIdx.x;
  const int kseg = lane >> 3;       // [0,8): 16 k rows each
  const int vs = lane & 7;          // [0,8): 1 v col each
  const int kh = h >> 1;

  const float* qp = mix + (size_t)b * SEQ * CONVD + (size_t)kh * DKH + kseg * 16;
  const float* kp = qp + KEYD;
  const float* vp = mix + (size_t)b * SEQ * CONVD + 2 * KEYD + (size_t)h * DVH + vc * 8 + vs;
  const float2* gp = (const float2*)(gate2) + (size_t)b * SEQ * 32 + h;
  float* orow = core + (size_t)b * SEQ * VALD + (size_t)h * DVH + vc * 8 + vs;
  const int outl = (kseg == 0);

  float st[16];
  #pragma unroll
  for (int i = 0; i < 16; i++) st[i] = 0.f;

  Frag2 F0, F1, F2, F3;
  load_frag2(F0, kp, qp, vp, gp, 0);
  load_frag2(F1, kp, qp, vp, gp, 1);
  load_frag2(F2, kp, qp, vp, gp, 2);
  load_frag2(F3, kp, qp, vp, gp, 3);

  int s = 0;
  for (; s < SEQ - 4; s += 4) {
    scan_step(F0, st, orow, s, outl);
    __builtin_amdgcn_sched_barrier(0);
    load_frag2(F0, kp, qp, vp, gp, s + 4);
    __builtin_amdgcn_sched_barrier(0);
    scan_step(F1, st, orow, s + 1, outl);
    __builtin_amdgcn_sched_barrier(0);
    load_frag2(F1, kp, qp, vp, gp, s + 5);
    __builtin_amdgcn_sched_barrier(0);
    scan_step(F2, st, orow, s + 2, outl);
    __builtin_amdgcn_sched_barrier(0);
    load_frag2(F2, kp, qp, vp, gp, s + 6);
    __builtin_amdgcn_sched_barrier(0);
    scan_step(F3, st, orow, s + 3, outl);
    __builtin_amdgcn_sched_barrier(0);
    load_frag2(F3, kp, qp, vp, gp, s + 7);
    __builtin_amdgcn_sched_barrier(0);
  }
  // epilogue: steps SEQ-4 .. SEQ-1 (all frags already loaded, no more loads)
  scan_step(F0, st, orow, SEQ - 4, outl);
  scan_step(F1, st, orow, SEQ - 3, outl);
  scan_step(F2, st, orow, SEQ - 2, outl);
  scan_step(F3, st, orow, SEQ - 1, outl);
}

// ------------- RMSNorm(1+w) * silu(z) -> bf16 -------------
__global__ __launch_bounds__(256) void rmsnorm_silu(
    const float* __restrict__ core, const float* __restrict__ zbuf,
    const float* __restrict__ norm_w, ushort* __restrict__ out_bf) {
  int t = blockIdx.x;
  int tid = threadIdx.x;
  const float* row = core + (size_t)t * VALD;
  const float* zrow = zbuf + (size_t)t * VALD;
  ushort* orow = out_bf + (size_t)t * VALD;
  float vals[16];
  float ss = 0.f;
  #pragma unroll
  for (int i = 0; i < 16; i++) { float x = row[tid + i * 256]; vals[i] = x; ss += x * x; }
  #pragma unroll
  for (int off = 32; off >= 1; off >>= 1) ss += __shfl_xor(ss, off, 64);
  __shared__ float red[4];
  if ((tid & 63) == 0) red[tid >> 6] = ss;
  __syncthreads();
  float tot = red[0] + red[1] + red[2] + red[3];
  float scale = rsqrtf(tot * (1.f / VALD) + EPSF);
  #pragma unroll
  for (int i = 0; i < 16; i++) {
    int c = tid + i * 256;
    float z = zrow[c];
    float sz = z / (1.f + expf(-z));
    orow[c] = f2bf(vals[i] * scale * (1.f + norm_w[c]) * sz);
  }
}

extern "C" void kernel_launch(void* const* d_in, const int* in_sizes, int n_in,
                              void* d_out, int out_size, void* d_ws, size_t ws_size,
                              hipStream_t stream) {
  const float* x       = (const float*)d_in[0];
  const float* W_qkvz  = (const float*)d_in[1];
  const float* W_ba    = (const float*)d_in[2];
  const float* conv_w  = (const float*)d_in[3];
  const float* dt_bias = (const float*)d_in[4];
  const float* A_log   = (const float*)d_in[5];
  const float* norm_w  = (const float*)d_in[6];
  const float* W_out   = (const float*)d_in[7];
  float* out = (float*)d_out;

  // workspace layout (floats), total 84,410,368 fl = 337.6 MB
  float* ws = (float*)d_ws;
  float* A  = ws;                         // 33,554,432 fl
  float* Bp = A + (size_t)33554432;       // 33,554,432 fl
  float* Cp = Bp + (size_t)33554432;      // 16,777,216 fl
  float* ba = Cp + (size_t)16777216;      //    262,144 fl
  float* g2 = ba + (size_t)262144;        //    262,144 fl (float2[TOK*32])

  ushort* x_bf    = (ushort*)Cp;
  ushort* Wqkv_bf = (ushort*)Bp;
  float*  zb      = A;
  ushort* core_bf = (ushort*)(A + (size_t)16777216);
  ushort* Wz_bf   = (ushort*)(A + (size_t)25165824);
  ushort* Wo_bf   = (ushort*)Bp;
  float*  mix     = Bp;
  float*  core    = Cp;

  // 1) casts for qkv projection
  cast_bf16<<<(TOK * HS / 4 + 255) / 256, 256, 0, stream>>>((const float4*)x, (ushort4*)x_bf, TOK * HS / 4);
  cast_bf16<<<(CONVD * HS / 4 + 255) / 256, 256, 0, stream>>>((const float4*)W_qkvz, (ushort4*)Wqkv_bf, CONVD * HS / 4);
  // 2) qkv projection (bf16 MFMA): [TOK, 8192]
  gemm_bf16_nt<<<dim3(CONVD / 128, TOK / 128), 256, 0, stream>>>(x_bf, Wqkv_bf, A, TOK, CONVD, HS);
  // 3) ba projection (fp32, tiny)
  gemm_nt<<<dim3(1, TOK / 64), 256, 0, stream>>>(x, W_ba, ba, TOK, 64, HS);
  // 4) conv + silu: A -> mix (frees A, overwrites Wqkv_bf in Bp)
  conv_silu<<<(int)(((size_t)TOK * CONVD) / 256), 256, 0, stream>>>(A, conv_w, mix);
  // 5) z projection: cast z-rows of W_qkvz, GEMM into A
  cast_bf16<<<(VALD * HS / 4 + 255) / 256, 256, 0, stream>>>(
      (const float4*)(W_qkvz + (size_t)(2 * KEYD + VALD) * HS), (ushort4*)Wz_bf, VALD * HS / 4);
  gemm_bf16_nt<<<dim3(VALD / 128, TOK / 128), 256, 0, stream>>>(x_bf, Wz_bf, zb, TOK, VALD, HS);
  // 6) gates -> float2 buffer
  gates_kernel<<<TOK * NVH / 256, 256, 0, stream>>>(ba, A_log, dt_bias, (float2*)g2);
  // 7) l2 norm q,k (in place in mix)
  l2norm_qk<<<TOK * 32 / 4, 256, 0, stream>>>(mix);
  // 8) scan v5: all-VALU butterfly (DPP + permlane swaps), ring-4 prefetch
  scan_kernel<<<NBATCH * NVH * 16, 64, 0, stream>>>(mix, g2, core);
  // 9) rmsnorm * silu(z) -> bf16
  rmsnorm_silu<<<TOK, 256, 0, stream>>>(core, zb, norm_w, core_bf);
  // 10) output projection
  cast_bf16<<<(HS * VALD / 4 + 255) / 256, 256, 0, stream>>>((const float4*)W_out, (ushort4*)Wo_bf, HS * VALD / 4);
  gemm_bf16_nt<<<dim3(HS / 128, TOK / 128), 256, 0, stream>>>(core_bf, Wo_bf, out, TOK, HS, VALD);
}

// Round 3
// 1187.636 us; speedup vs baseline: 1.8938x; 1.5869x over previous
//
#include <hip/hip_runtime.h>
#include <hip/hip_bf16.h>
#include <math.h>

#define TOK    4096   // B*S
#define HS     2048
#define CONVD  8192
#define KEYD   2048
#define VALD   4096
#define NKH    16
#define NVH    32
#define DKH    128
#define DVH    128
#define SEQ    2048
#define NBATCH 2
#define EPSF   1e-6f
#define CHUNK  64
#define NCHUNK 32

typedef __attribute__((ext_vector_type(8))) short short8;
typedef __attribute__((ext_vector_type(4))) float floatx4;

static __device__ __forceinline__ unsigned short f2bf(float x) {
  union { float f; unsigned u; } c; c.f = x;
  unsigned r = (c.u + 0x7FFF + ((c.u >> 16) & 1)) >> 16;
  return (unsigned short)r;
}
static __device__ __forceinline__ float bf2f(unsigned short u) {
  union { unsigned u; float f; } c; c.u = ((unsigned)u) << 16;
  return c.f;
}

// ---------------- fp32 GEMM (tiny ba projection only) ----------------
__global__ __launch_bounds__(256) void gemm_nt(
    const float* __restrict__ A, const float* __restrict__ B,
    float* __restrict__ C, int M, int N, int K) {
  __shared__ float As[16][68];
  __shared__ float Bs[16][68];
  const int tx = threadIdx.x & 15;
  const int ty = threadIdx.x >> 4;
  const int row0 = blockIdx.y * 64;
  const int col0 = blockIdx.x * 64;
  const int lr = threadIdx.x >> 2;
  const int lc = (threadIdx.x & 3) * 4;
  float acc[4][4] = {};
  for (int k0 = 0; k0 < K; k0 += 16) {
    float4 av = *(const float4*)&A[(size_t)(row0 + lr) * K + (k0 + lc)];
    float4 bv = *(const float4*)&B[(size_t)(col0 + lr) * K + (k0 + lc)];
    As[lc + 0][lr] = av.x; As[lc + 1][lr] = av.y;
    As[lc + 2][lr] = av.z; As[lc + 3][lr] = av.w;
    Bs[lc + 0][lr] = bv.x; Bs[lc + 1][lr] = bv.y;
    Bs[lc + 2][lr] = bv.z; Bs[lc + 3][lr] = bv.w;
    __syncthreads();
    #pragma unroll
    for (int kk = 0; kk < 16; kk++) {
      float a[4], b[4];
      #pragma unroll
      for (int i = 0; i < 4; i++) a[i] = As[kk][ty * 4 + i];
      #pragma unroll
      for (int i = 0; i < 4; i++) b[i] = Bs[kk][tx * 4 + i];
      #pragma unroll
      for (int i = 0; i < 4; i++)
        #pragma unroll
        for (int j = 0; j < 4; j++)
          acc[i][j] += a[i] * b[j];
    }
    __syncthreads();
  }
  #pragma unroll
  for (int i = 0; i < 4; i++) {
    float4 v = make_float4(acc[i][0], acc[i][1], acc[i][2], acc[i][3]);
    *(float4*)&C[(size_t)(row0 + ty * 4 + i) * N + (col0 + tx * 4)] = v;
  }
}

// ---------------- fp32 -> bf16 cast ----------------
__global__ __launch_bounds__(256) void cast_bf16(
    const float4* __restrict__ src, ushort4* __restrict__ dst, int n4) {
  int i = blockIdx.x * 256 + threadIdx.x;
  if (i < n4) {
    float4 v = src[i];
    ushort4 o;
    o.x = f2bf(v.x); o.y = f2bf(v.y); o.z = f2bf(v.z); o.w = f2bf(v.w);
    dst[i] = o;
  }
}

// ---------------- bf16 MFMA GEMM: C[M,N] = A[M,K] * B[N,K]^T ----------------
__global__ __launch_bounds__(256) void gemm_bf16_nt(
    const ushort* __restrict__ A, const ushort* __restrict__ B,
    float* __restrict__ C, int M, int N, int K) {
  __shared__ ushort Asm[128 * 32];
  __shared__ ushort Bsm[128 * 32];
  const int tid = threadIdx.x;
  const int w = tid >> 6, l = tid & 63;
  const int row0 = blockIdx.y * 128, col0 = blockIdx.x * 128;
  const int wm = w >> 1, wn = w & 1;

  floatx4 acc[4][4];
  #pragma unroll
  for (int i = 0; i < 4; i++)
    #pragma unroll
    for (int j = 0; j < 4; j++)
      acc[i][j] = (floatx4){0.f, 0.f, 0.f, 0.f};

  const int srow = w * 16 + (l >> 2);
  const int scol = (l & 3) * 8;
  const ushort* Ag = A + (size_t)(row0 + srow) * K + scol;
  const ushort* Bg = B + (size_t)(col0 + srow) * K + scol;

  for (int k0 = 0; k0 < K; k0 += 32) {
    #pragma unroll
    for (int c = 0; c < 2; c++) {
      __builtin_amdgcn_global_load_lds(
          (const __attribute__((address_space(1))) void*)(Ag + (size_t)(c * 64) * K + k0),
          (__attribute__((address_space(3))) void*)&Asm[(c * 64 + w * 16) * 32],
          16, 0, 0);
      __builtin_amdgcn_global_load_lds(
          (const __attribute__((address_space(1))) void*)(Bg + (size_t)(c * 64) * K + k0),
          (__attribute__((address_space(3))) void*)&Bsm[(c * 64 + w * 16) * 32],
          16, 0, 0);
    }
    __syncthreads();
    short8 af[4], bfv[4];
    #pragma unroll
    for (int i = 0; i < 4; i++) {
      af[i]  = *(const short8*)&Asm[(wm * 64 + i * 16 + (l & 15)) * 32 + (l >> 4) * 8];
      bfv[i] = *(const short8*)&Bsm[(wn * 64 + i * 16 + (l & 15)) * 32 + (l >> 4) * 8];
    }
    #pragma unroll
    for (int i = 0; i < 4; i++)
      #pragma unroll
      for (int j = 0; j < 4; j++)
        acc[i][j] = __builtin_amdgcn_mfma_f32_16x16x32_bf16(af[i], bfv[j], acc[i][j], 0, 0, 0);
    __syncthreads();
  }

  const int cl = l & 15, rq = l >> 4;
  #pragma unroll
  for (int i = 0; i < 4; i++) {
    int r0 = row0 + wm * 64 + i * 16 + rq * 4;
    #pragma unroll
    for (int j = 0; j < 4; j++) {
      int cc = col0 + wn * 64 + j * 16 + cl;
      #pragma unroll
      for (int r = 0; r < 4; r++)
        C[(size_t)(r0 + r) * N + cc] = acc[i][j][r];
    }
  }
}

// ------------- causal depthwise conv (K=4) + SiLU -------------
__global__ __launch_bounds__(256) void conv_silu(
    const float* __restrict__ qkv, const float* __restrict__ cw,
    float* __restrict__ mix) {
  size_t idx = (size_t)blockIdx.x * 256 + threadIdx.x;
  int c = (int)(idx % CONVD);
  size_t t = idx / CONVD;
  int s = (int)(t % SEQ);
  float w0 = cw[c * 4 + 0], w1 = cw[c * 4 + 1], w2 = cw[c * 4 + 2], w3 = cw[c * 4 + 3];
  const float* col = qkv + t * CONVD + c;
  float acc = w3 * col[0];
  if (s >= 1) acc += w2 * col[-(ptrdiff_t)CONVD];
  if (s >= 2) acc += w1 * col[-2 * (ptrdiff_t)CONVD];
  if (s >= 3) acc += w0 * col[-3 * (ptrdiff_t)CONVD];
  float sig = 1.f / (1.f + expf(-acc));
  mix[t * CONVD + c] = acc * sig;
}

// ------------- gates: write float2 {lg, beta} per (t, h) -------------
// lg = log of the decay gate (pre-exp) — chunked scan works in log space.
__global__ __launch_bounds__(256) void gates_kernel(
    const float* __restrict__ ba, const float* __restrict__ A_log,
    const float* __restrict__ dt_bias, float2* __restrict__ g2) {
  int idx = blockIdx.x * 256 + threadIdx.x;
  int h = idx & 31;
  size_t t = (size_t)(idx >> 5);
  float bv = ba[t * 64 + h];
  float av = ba[t * 64 + 32 + h];
  float beta = 1.f / (1.f + expf(-bv));
  float xx = av + dt_bias[h];
  float sp = (xx > 20.f) ? xx : log1pf(expf(xx));
  float lg = -expf(A_log[h]) * sp;
  g2[t * 32 + h] = make_float2(lg, beta);
}

// ------------- per-head L2 norm of q and k (in place in mix) -------------
__global__ __launch_bounds__(256) void l2norm_qk(float* __restrict__ mix) {
  int wid = (blockIdx.x * 256 + threadIdx.x) >> 6;
  int lane = threadIdx.x & 63;
  size_t t = (size_t)(wid >> 5);
  int hh = wid & 31;
  float* p = mix + t * CONVD + (size_t)hh * DKH;
  float v0 = p[lane], v1 = p[lane + 64];
  float ss = v0 * v0 + v1 * v1;
  #pragma unroll
  for (int off = 32; off >= 1; off >>= 1) ss += __shfl_xor(ss, off, 64);
  float sc = rsqrtf(ss + EPSF);
  p[lane] = v0 * sc;
  p[lane + 64] = v1 * sc;
}

// ================= chunked delta-rule scan =================
// P1: per (b,h,chunk): Lg prefix, A = strict-lower beta_i e^{Lg_i-Lg_j} (k_i.k_j),
//     T = (I+A)^{-1} (forward substitution), M = incl-lower e^{Lg_i-Lg_j}(q_i.k_j).
// grid 2048 = b(2) x h(32) x ch(32); 64 threads (1 wave).
__global__ __launch_bounds__(64) void chunk_prep(
    const float* __restrict__ mix, const float2* __restrict__ g2,
    float* __restrict__ Lgbuf, ushort* __restrict__ Tbuf,
    ushort* __restrict__ Mbuf) {
  const int blk = blockIdx.x;            // b*1024 + h*32 + ch
  const int ch = blk & 31;
  const int h  = (blk >> 5) & 31;
  const int b  = blk >> 10;
  const int kh = h >> 1;
  const int l  = threadIdx.x;
  const int fr = l & 15;
  const int fc8 = (l >> 4) * 8;
  const int cr = (l >> 4) * 4;

  __shared__ float sLg[64], sB[64];
  __shared__ float sA[64 * 65];
  __shared__ float sT[64 * 65];

  // gate prefix (inclusive log-cumsum over the 64 chunk tokens)
  float2 gv = g2[((size_t)(b * SEQ + ch * 64 + l)) * 32 + h];
  float lg = gv.x;
  #pragma unroll
  for (int off = 1; off < 64; off <<= 1) {
    float n = __shfl_up(lg, off, 64);
    if (l >= off) lg += n;
  }
  sLg[l] = lg; sB[l] = gv.y;
  Lgbuf[(size_t)blk * 64 + l] = lg;
  __syncthreads();

  const float* kb = mix + ((size_t)(b * SEQ + ch * 64)) * CONVD + KEYD + (size_t)kh * DKH;
  const float* qb = mix + ((size_t)(b * SEQ + ch * 64)) * CONVD + (size_t)kh * DKH;

  floatx4 zero4 = {0.f, 0.f, 0.f, 0.f};
  floatx4 kk[4][4], qk[4][4];
  #pragma unroll
  for (int i = 0; i < 4; i++)
    #pragma unroll
    for (int j = 0; j < 4; j++) { kk[i][j] = zero4; qk[i][j] = zero4; }

  for (int ks = 0; ks < 4; ks++) {
    short8 kf[4], qf[4];
    #pragma unroll
    for (int m = 0; m < 4; m++) {
      const float* kp = kb + (size_t)(m * 16 + fr) * CONVD + fc8 + ks * 32;
      const float* qp = qb + (size_t)(m * 16 + fr) * CONVD + fc8 + ks * 32;
      float4 a0 = *(const float4*)kp, a1 = *(const float4*)(kp + 4);
      float4 c0 = *(const float4*)qp, c1 = *(const float4*)(qp + 4);
      short8 kv, qv;
      kv[0]=(short)f2bf(a0.x); kv[1]=(short)f2bf(a0.y); kv[2]=(short)f2bf(a0.z); kv[3]=(short)f2bf(a0.w);
      kv[4]=(short)f2bf(a1.x); kv[5]=(short)f2bf(a1.y); kv[6]=(short)f2bf(a1.z); kv[7]=(short)f2bf(a1.w);
      qv[0]=(short)f2bf(c0.x); qv[1]=(short)f2bf(c0.y); qv[2]=(short)f2bf(c0.z); qv[3]=(short)f2bf(c0.w);
      qv[4]=(short)f2bf(c1.x); qv[5]=(short)f2bf(c1.y); qv[6]=(short)f2bf(c1.z); qv[7]=(short)f2bf(c1.w);
      kf[m] = kv; qf[m] = qv;
    }
    #pragma unroll
    for (int mt = 0; mt < 4; mt++)
      #pragma unroll
      for (int nt = 0; nt < 4; nt++) {
        kk[mt][nt] = __builtin_amdgcn_mfma_f32_16x16x32_bf16(kf[mt], kf[nt], kk[mt][nt], 0, 0, 0);
        qk[mt][nt] = __builtin_amdgcn_mfma_f32_16x16x32_bf16(qf[mt], kf[nt], qk[mt][nt], 0, 0, 0);
      }
  }

  // scale + scatter A (LDS) and M (global bf16)
  const size_t tmbase = (size_t)blk * 4096;
  #pragma unroll
  for (int mt = 0; mt < 4; mt++)
    #pragma unroll
    for (int r = 0; r < 4; r++) {
      int i = mt * 16 + cr + r;
      float Li = sLg[i], Bi = sB[i];
      #pragma unroll
      for (int nt = 0; nt < 4; nt++) {
        int j = nt * 16 + fr;
        float dec = expf(Li - sLg[j]);
        sA[i * 65 + j] = (j < i) ? Bi * dec * kk[mt][nt][r] : 0.f;
        float mv = (j <= i) ? dec * qk[mt][nt][r] : 0.f;
        Mbuf[tmbase + (size_t)i * 64 + j] = f2bf(mv);
      }
    }
  __syncthreads();

  // T = (I+A)^{-1}: forward substitution; lane l owns column l (lane-private).
  sT[0 * 65 + l] = (l == 0) ? 1.f : 0.f;
  for (int i = 1; i < 64; i++) {
    float acc = (l == i) ? 1.f : 0.f;
    for (int j = 0; j < i; j++)
      acc -= sA[i * 65 + j] * sT[j * 65 + l];
    sT[i * 65 + l] = acc;
  }
  for (int i = 0; i < 64; i++)
    Tbuf[tmbase + (size_t)i * 64 + l] = f2bf(sT[i * 65 + l]);
}

// P2: sequential over 32 chunks; state [128k, 32v] in fp32 MFMA accumulators.
// grid 256 = bh(64) x vq(4); 256 threads (4 waves, waves split the M dim).
// S and Delta bounce through LDS as hi+lo split-bf16 (fp32-accurate products).
__global__ __launch_bounds__(256) void chunk_scan(
    const float* __restrict__ mix, const float2* __restrict__ g2,
    const float* __restrict__ Lgbuf, const ushort* __restrict__ Tbuf,
    const ushort* __restrict__ Mbuf, float* __restrict__ core) {
  const int blk = blockIdx.x;
  const int vq = blk & 3;
  const int bh = blk >> 2;
  const int h = bh & 31;
  const int b = bh >> 5;
  const int kh = h >> 1;
  const int tid = threadIdx.x;
  const int w = tid >> 6;
  const int l = tid & 63;
  const int fr = l & 15;
  const int fc8 = (l >> 4) * 8;
  const int cr = (l >> 4) * 4;

  __shared__ ushort STh[32][136], STl[32][136];   // S^T [v][k], hi/lo bf16
  __shared__ ushort DTh[32][72],  DTl[32][72];    // R^T then Delta^T [v][i]
  __shared__ float sKB[64], sQv[64], sKh[64], sBe[64];
  __shared__ float sLgC;

  for (int i = tid; i < 32 * 136; i += 256) { (&STh[0][0])[i] = 0; (&STl[0][0])[i] = 0; }

  floatx4 zero4 = {0.f, 0.f, 0.f, 0.f};
  floatx4 sacc[2][2] = {{zero4, zero4}, {zero4, zero4}};

  const size_t mixb = (size_t)b * SEQ * CONVD;
  const float* kbase = mix + mixb + KEYD + (size_t)kh * DKH;
  const float* qbase = mix + mixb + (size_t)kh * DKH;
  const float* vbase = mix + mixb + 2 * KEYD + (size_t)h * DVH + vq * 32;
  float* cbase = core + (size_t)b * SEQ * VALD + (size_t)h * DVH + vq * 32;

  for (int ch = 0; ch < NCHUNK; ch++) {
    const int tok0 = ch * 64;
    const size_t tmbase = ((size_t)bh * 32 + ch) * 4096;
    if (tid < 64) {
      float Lgv = Lgbuf[((size_t)bh * 32 + ch) * 64 + tid];
      float LgC = Lgbuf[((size_t)bh * 32 + ch) * 64 + 63];
      float2 gv = g2[((size_t)(b * SEQ + tok0 + tid)) * 32 + h];
      float e = expf(Lgv);
      sKB[tid] = gv.y * e;
      sQv[tid] = e;
      sKh[tid] = expf(LgC - Lgv);
      sBe[tid] = gv.y;
      if (tid == 0) sLgC = LgC;
    }
    __syncthreads();                                   // bar A

    const int ia = w * 16 + fr;                        // A-operand token row
    // ---- (a) P = (beta*e^Lg K) . S0 ----
    floatx4 p[2] = {zero4, zero4};
    {
      const float* arow = kbase + (size_t)(tok0 + ia) * CONVD;
      float ascl = sKB[ia];
      #pragma unroll
      for (int ks = 0; ks < 4; ks++) {
        float4 x0 = *(const float4*)(arow + fc8 + ks * 32);
        float4 x1 = *(const float4*)(arow + fc8 + ks * 32 + 4);
        short8 af;
        af[0]=(short)f2bf(x0.x*ascl); af[1]=(short)f2bf(x0.y*ascl);
        af[2]=(short)f2bf(x0.z*ascl); af[3]=(short)f2bf(x0.w*ascl);
        af[4]=(short)f2bf(x1.x*ascl); af[5]=(short)f2bf(x1.y*ascl);
        af[6]=(short)f2bf(x1.z*ascl); af[7]=(short)f2bf(x1.w*ascl);
        #pragma unroll
        for (int nt = 0; nt < 2; nt++) {
          short8 bh_ = *(const short8*)&STh[nt * 16 + fr][fc8 + ks * 32];
          short8 bl_ = *(const short8*)&STl[nt * 16 + fr][fc8 + ks * 32];
          p[nt] = __builtin_amdgcn_mfma_f32_16x16x32_bf16(af, bh_, p[nt], 0, 0, 0);
          p[nt] = __builtin_amdgcn_mfma_f32_16x16x32_bf16(af, bl_, p[nt], 0, 0, 0);
        }
      }
    }
    // epilogue: R = beta*v - P -> DT (hi/lo)
    #pragma unroll
    for (int nt = 0; nt < 2; nt++)
      #pragma unroll
      for (int r = 0; r < 4; r++) {
        int i = w * 16 + cr + r;
        int v = nt * 16 + fr;
        float vv = vbase[(size_t)(tok0 + i) * CONVD + v];
        float Rv = sBe[i] * vv - p[nt][r];
        unsigned short hv = f2bf(Rv);
        DTh[v][i] = hv;
        DTl[v][i] = f2bf(Rv - bf2f(hv));
      }
    __syncthreads();                                   // bar B

    // ---- (b) Delta = T . R ----
    floatx4 d[2] = {zero4, zero4};
    #pragma unroll
    for (int ks = 0; ks < 2; ks++) {
      short8 af = *(const short8*)&Tbuf[tmbase + (size_t)ia * 64 + fc8 + ks * 32];
      #pragma unroll
      for (int nt = 0; nt < 2; nt++) {
        short8 bh_ = *(const short8*)&DTh[nt * 16 + fr][fc8 + ks * 32];
        short8 bl_ = *(const short8*)&DTl[nt * 16 + fr][fc8 + ks * 32];
        d[nt] = __builtin_amdgcn_mfma_f32_16x16x32_bf16(af, bh_, d[nt], 0, 0, 0);
        d[nt] = __builtin_amdgcn_mfma_f32_16x16x32_bf16(af, bl_, d[nt], 0, 0, 0);
      }
    }
    __syncthreads();                                   // bar C (RT reads done)
    #pragma unroll
    for (int nt = 0; nt < 2; nt++)
      #pragma unroll
      for (int r = 0; r < 4; r++) {
        int i = w * 16 + cr + r;
        int v = nt * 16 + fr;
        float dv = d[nt][r];
        unsigned short hv = f2bf(dv);
        DTh[v][i] = hv;
        DTl[v][i] = f2bf(dv - bf2f(hv));
      }
    __syncthreads();                                   // bar D

    // ---- (d) O = e^Lg Q . S0  +  (e) M . Delta ----
    floatx4 o[2] = {zero4, zero4};
    {
      const float* arow = qbase + (size_t)(tok0 + ia) * CONVD;
      float ascl = sQv[ia];
      #pragma unroll
      for (int ks = 0; ks < 4; ks++) {
        float4 x0 = *(const float4*)(arow + fc8 + ks * 32);
        float4 x1 = *(const float4*)(arow + fc8 + ks * 32 + 4);
        short8 af;
        af[0]=(short)f2bf(x0.x*ascl); af[1]=(short)f2bf(x0.y*ascl);
        af[2]=(short)f2bf(x0.z*ascl); af[3]=(short)f2bf(x0.w*ascl);
        af[4]=(short)f2bf(x1.x*ascl); af[5]=(short)f2bf(x1.y*ascl);
        af[6]=(short)f2bf(x1.z*ascl); af[7]=(short)f2bf(x1.w*ascl);
        #pragma unroll
        for (int nt = 0; nt < 2; nt++) {
          short8 bh_ = *(const short8*)&STh[nt * 16 + fr][fc8 + ks * 32];
          short8 bl_ = *(const short8*)&STl[nt * 16 + fr][fc8 + ks * 32];
          o[nt] = __builtin_amdgcn_mfma_f32_16x16x32_bf16(af, bh_, o[nt], 0, 0, 0);
          o[nt] = __builtin_amdgcn_mfma_f32_16x16x32_bf16(af, bl_, o[nt], 0, 0, 0);
        }
      }
      #pragma unroll
      for (int ks = 0; ks < 2; ks++) {
        short8 af = *(const short8*)&Mbuf[tmbase + (size_t)ia * 64 + fc8 + ks * 32];
        #pragma unroll
        for (int nt = 0; nt < 2; nt++) {
          short8 bh_ = *(const short8*)&DTh[nt * 16 + fr][fc8 + ks * 32];
          short8 bl_ = *(const short8*)&DTl[nt * 16 + fr][fc8 + ks * 32];
          o[nt] = __builtin_amdgcn_mfma_f32_16x16x32_bf16(af, bh_, o[nt], 0, 0, 0);
          o[nt] = __builtin_amdgcn_mfma_f32_16x16x32_bf16(af, bl_, o[nt], 0, 0, 0);
        }
      }
    }
    #pragma unroll
    for (int nt = 0; nt < 2; nt++)
      #pragma unroll
      for (int r = 0; r < 4; r++) {
        int i = w * 16 + cr + r;
        int v = nt * 16 + fr;
        cbase[(size_t)(tok0 + i) * VALD + v] = o[nt][r];
      }

    // ---- (c) S = e^LgC * S + (e^{LgC-Lg} K)^T . Delta ----
    float eL = expf(sLgC);
    #pragma unroll
    for (int mt = 0; mt < 2; mt++)
      #pragma unroll
      for (int nt = 0; nt < 2; nt++)
        sacc[mt][nt] = sacc[mt][nt] * eL;
    #pragma unroll
    for (int ks = 0; ks < 2; ks++) {
      float kh8[8];
      #pragma unroll
      for (int jj = 0; jj < 8; jj++) kh8[jj] = sKh[fc8 + ks * 32 + jj];
      short8 afm[2];
      #pragma unroll
      for (int mt = 0; mt < 2; mt++) {
        int krow = w * 32 + mt * 16 + fr;
        short8 a;
        #pragma unroll
        for (int jj = 0; jj < 8; jj++) {
          float kvv = kbase[(size_t)(tok0 + fc8 + ks * 32 + jj) * CONVD + krow];
          a[jj] = (short)f2bf(kvv * kh8[jj]);
        }
        afm[mt] = a;
      }
      #pragma unroll
      for (int mt = 0; mt < 2; mt++)
        #pragma unroll
        for (int nt = 0; nt < 2; nt++) {
          short8 bh_ = *(const short8*)&DTh[nt * 16 + fr][fc8 + ks * 32];
          short8 bl_ = *(const short8*)&DTl[nt * 16 + fr][fc8 + ks * 32];
          sacc[mt][nt] = __builtin_amdgcn_mfma_f32_16x16x32_bf16(afm[mt], bh_, sacc[mt][nt], 0, 0, 0);
          sacc[mt][nt] = __builtin_amdgcn_mfma_f32_16x16x32_bf16(afm[mt], bl_, sacc[mt][nt], 0, 0, 0);
        }
    }
    __syncthreads();                                   // bar E (ST/DT reads done)
    #pragma unroll
    for (int mt = 0; mt < 2; mt++)
      #pragma unroll
      for (int nt = 0; nt < 2; nt++)
        #pragma unroll
        for (int r = 0; r < 4; r++) {
          int k = w * 32 + mt * 16 + cr + r;
          int v = nt * 16 + fr;
          float sv = sacc[mt][nt][r];
          unsigned short hv = f2bf(sv);
          STh[v][k] = hv;
          STl[v][k] = f2bf(sv - bf2f(hv));
        }
    // next iteration's bar A orders these writes vs. (a)'s reads
  }
}

// ------------- RMSNorm(1+w) * silu(z) -> bf16 -------------
__global__ __launch_bounds__(256) void rmsnorm_silu(
    const float* __restrict__ core, const float* __restrict__ zbuf,
    const float* __restrict__ norm_w, ushort* __restrict__ out_bf) {
  int t = blockIdx.x;
  int tid = threadIdx.x;
  const float* row = core + (size_t)t * VALD;
  const float* zrow = zbuf + (size_t)t * VALD;
  ushort* orow = out_bf + (size_t)t * VALD;
  float vals[16];
  float ss = 0.f;
  #pragma unroll
  for (int i = 0; i < 16; i++) { float x = row[tid + i * 256]; vals[i] = x; ss += x * x; }
  #pragma unroll
  for (int off = 32; off >= 1; off >>= 1) ss += __shfl_xor(ss, off, 64);
  __shared__ float red[4];
  if ((tid & 63) == 0) red[tid >> 6] = ss;
  __syncthreads();
  float tot = red[0] + red[1] + red[2] + red[3];
  float scale = rsqrtf(tot * (1.f / VALD) + EPSF);
  #pragma unroll
  for (int i = 0; i < 16; i++) {
    int c = tid + i * 256;
    float z = zrow[c];
    float sz = z / (1.f + expf(-z));
    orow[c] = f2bf(vals[i] * scale * (1.f + norm_w[c]) * sz);
  }
}

extern "C" void kernel_launch(void* const* d_in, const int* in_sizes, int n_in,
                              void* d_out, int out_size, void* d_ws, size_t ws_size,
                              hipStream_t stream) {
  const float* x       = (const float*)d_in[0];
  const float* W_qkvz  = (const float*)d_in[1];
  const float* W_ba    = (const float*)d_in[2];
  const float* conv_w  = (const float*)d_in[3];
  const float* dt_bias = (const float*)d_in[4];
  const float* A_log   = (const float*)d_in[5];
  const float* norm_w  = (const float*)d_in[6];
  const float* W_out   = (const float*)d_in[7];
  float* out = (float*)d_out;

  // workspace layout (floats), total 84,410,368 fl = 337.6 MB
  float* ws = (float*)d_ws;
  float* A  = ws;                         // 33,554,432 fl
  float* Bp = A + (size_t)33554432;       // 33,554,432 fl
  float* Cp = Bp + (size_t)33554432;      // 16,777,216 fl
  float* ba = Cp + (size_t)16777216;      //    262,144 fl
  float* g2 = ba + (size_t)262144;        //    262,144 fl (float2[TOK*32])

  ushort* x_bf    = (ushort*)Cp;
  ushort* Wqkv_bf = (ushort*)Bp;
  float*  zb      = A;                    // A[0 .. 16,777,216)
  ushort* core_bf = (ushort*)(A + (size_t)16777216);   // used after scan only
  ushort* Wz_bf   = (ushort*)(A + (size_t)25165824);   // used before scan only
  ushort* Wo_bf   = (ushort*)Bp;
  float*  mix     = Bp;
  float*  core    = Cp;
  // chunked-scan buffers in A-upper (dead regions during scan phase):
  ushort* Tbuf    = (ushort*)(A + (size_t)16777216);   // 2048*4096 ushort = 4,194,304 fl
  ushort* Mbuf    = (ushort*)(A + (size_t)20971520);   // 4,194,304 fl
  float*  Lgbuf   = A + (size_t)29360128;              // 131,072 fl

  // 1) casts for qkv projection
  cast_bf16<<<(TOK * HS / 4 + 255) / 256, 256, 0, stream>>>((const float4*)x, (ushort4*)x_bf, TOK * HS / 4);
  cast_bf16<<<(CONVD * HS / 4 + 255) / 256, 256, 0, stream>>>((const float4*)W_qkvz, (ushort4*)Wqkv_bf, CONVD * HS / 4);
  // 2) qkv projection (bf16 MFMA): [TOK, 8192]
  gemm_bf16_nt<<<dim3(CONVD / 128, TOK / 128), 256, 0, stream>>>(x_bf, Wqkv_bf, A, TOK, CONVD, HS);
  // 3) ba projection (fp32, tiny)
  gemm_nt<<<dim3(1, TOK / 64), 256, 0, stream>>>(x, W_ba, ba, TOK, 64, HS);
  // 4) conv + silu: A -> mix
  conv_silu<<<(int)(((size_t)TOK * CONVD) / 256), 256, 0, stream>>>(A, conv_w, mix);
  // 5) z projection: cast z-rows of W_qkvz, GEMM into A
  cast_bf16<<<(VALD * HS / 4 + 255) / 256, 256, 0, stream>>>(
      (const float4*)(W_qkvz + (size_t)(2 * KEYD + VALD) * HS), (ushort4*)Wz_bf, VALD * HS / 4);
  gemm_bf16_nt<<<dim3(VALD / 128, TOK / 128), 256, 0, stream>>>(x_bf, Wz_bf, zb, TOK, VALD, HS);
  // 6) gates -> float2 {lg, beta}
  gates_kernel<<<TOK * NVH / 256, 256, 0, stream>>>(ba, A_log, dt_bias, (float2*)g2);
  // 7) l2 norm q,k (in place in mix)
  l2norm_qk<<<TOK * 32 / 4, 256, 0, stream>>>(mix);
  // 8) chunked delta-rule scan: parallel prep + sequential chunk GEMMs
  chunk_prep<<<NBATCH * NVH * NCHUNK, 64, 0, stream>>>(mix, (const float2*)g2, Lgbuf, Tbuf, Mbuf);
  chunk_scan<<<NBATCH * NVH * 4, 256, 0, stream>>>(mix, (const float2*)g2, Lgbuf, Tbuf, Mbuf, core);
  // 9) rmsnorm * silu(z) -> bf16
  rmsnorm_silu<<<TOK, 256, 0, stream>>>(core, zb, norm_w, core_bf);
  // 10) output projection
  cast_bf16<<<(HS * VALD / 4 + 255) / 256, 256, 0, stream>>>((const float4*)W_out, (ushort4*)Wo_bf, HS * VALD / 4);
  gemm_bf16_nt<<<dim3(HS / 128, TOK / 128), 256, 0, stream>>>(core_bf, Wo_bf, out, TOK, HS, VALD);
}

// Round 4
// 1105.528 us; speedup vs baseline: 2.0344x; 1.0743x over previous
//
#include <hip/hip_runtime.h>
#include <hip/hip_bf16.h>
#include <math.h>

#define TOK    4096   // B*S
#define HS     2048
#define CONVD  8192
#define KEYD   2048
#define VALD   4096
#define NKH    16
#define NVH    32
#define DKH    128
#define DVH    128
#define SEQ    2048
#define NBATCH 2
#define EPSF   1e-6f
#define CHUNK  64
#define NCHUNK 32

typedef __attribute__((ext_vector_type(8))) short short8;
typedef __attribute__((ext_vector_type(4))) float floatx4;

static __device__ __forceinline__ unsigned short f2bf(float x) {
  union { float f; unsigned u; } c; c.f = x;
  unsigned r = (c.u + 0x7FFF + ((c.u >> 16) & 1)) >> 16;
  return (unsigned short)r;
}
static __device__ __forceinline__ float bf2f(unsigned short u) {
  union { unsigned u; float f; } c; c.u = ((unsigned)u) << 16;
  return c.f;
}

// raw workgroup barrier: orders LDS (lgkmcnt) but does NOT drain vmcnt —
// global register-prefetch loads stay in flight across it.
#define BAR() do { \
  __builtin_amdgcn_sched_barrier(0); \
  asm volatile("s_waitcnt lgkmcnt(0)" ::: "memory"); \
  __builtin_amdgcn_s_barrier(); \
  __builtin_amdgcn_sched_barrier(0); \
} while (0)

// ---------------- fp32 GEMM (tiny ba projection only) ----------------
__global__ __launch_bounds__(256) void gemm_nt(
    const float* __restrict__ A, const float* __restrict__ B,
    float* __restrict__ C, int M, int N, int K) {
  __shared__ float As[16][68];
  __shared__ float Bs[16][68];
  const int tx = threadIdx.x & 15;
  const int ty = threadIdx.x >> 4;
  const int row0 = blockIdx.y * 64;
  const int col0 = blockIdx.x * 64;
  const int lr = threadIdx.x >> 2;
  const int lc = (threadIdx.x & 3) * 4;
  float acc[4][4] = {};
  for (int k0 = 0; k0 < K; k0 += 16) {
    float4 av = *(const float4*)&A[(size_t)(row0 + lr) * K + (k0 + lc)];
    float4 bv = *(const float4*)&B[(size_t)(col0 + lr) * K + (k0 + lc)];
    As[lc + 0][lr] = av.x; As[lc + 1][lr] = av.y;
    As[lc + 2][lr] = av.z; As[lc + 3][lr] = av.w;
    Bs[lc + 0][lr] = bv.x; Bs[lc + 1][lr] = bv.y;
    Bs[lc + 2][lr] = bv.z; Bs[lc + 3][lr] = bv.w;
    __syncthreads();
    #pragma unroll
    for (int kk = 0; kk < 16; kk++) {
      float a[4], b[4];
      #pragma unroll
      for (int i = 0; i < 4; i++) a[i] = As[kk][ty * 4 + i];
      #pragma unroll
      for (int i = 0; i < 4; i++) b[i] = Bs[kk][tx * 4 + i];
      #pragma unroll
      for (int i = 0; i < 4; i++)
        #pragma unroll
        for (int j = 0; j < 4; j++)
          acc[i][j] += a[i] * b[j];
    }
    __syncthreads();
  }
  #pragma unroll
  for (int i = 0; i < 4; i++) {
    float4 v = make_float4(acc[i][0], acc[i][1], acc[i][2], acc[i][3]);
    *(float4*)&C[(size_t)(row0 + ty * 4 + i) * N + (col0 + tx * 4)] = v;
  }
}

// ---------------- fp32 -> bf16 cast ----------------
__global__ __launch_bounds__(256) void cast_bf16(
    const float4* __restrict__ src, ushort4* __restrict__ dst, int n4) {
  int i = blockIdx.x * 256 + threadIdx.x;
  if (i < n4) {
    float4 v = src[i];
    ushort4 o;
    o.x = f2bf(v.x); o.y = f2bf(v.y); o.z = f2bf(v.z); o.w = f2bf(v.w);
    dst[i] = o;
  }
}

// ---------------- bf16 MFMA GEMM: C[M,N] = A[M,K] * B[N,K]^T ----------------
__global__ __launch_bounds__(256) void gemm_bf16_nt(
    const ushort* __restrict__ A, const ushort* __restrict__ B,
    float* __restrict__ C, int M, int N, int K) {
  __shared__ ushort Asm[128 * 32];
  __shared__ ushort Bsm[128 * 32];
  const int tid = threadIdx.x;
  const int w = tid >> 6, l = tid & 63;
  const int row0 = blockIdx.y * 128, col0 = blockIdx.x * 128;
  const int wm = w >> 1, wn = w & 1;

  floatx4 acc[4][4];
  #pragma unroll
  for (int i = 0; i < 4; i++)
    #pragma unroll
    for (int j = 0; j < 4; j++)
      acc[i][j] = (floatx4){0.f, 0.f, 0.f, 0.f};

  const int srow = w * 16 + (l >> 2);
  const int scol = (l & 3) * 8;
  const ushort* Ag = A + (size_t)(row0 + srow) * K + scol;
  const ushort* Bg = B + (size_t)(col0 + srow) * K + scol;

  for (int k0 = 0; k0 < K; k0 += 32) {
    #pragma unroll
    for (int c = 0; c < 2; c++) {
      __builtin_amdgcn_global_load_lds(
          (const __attribute__((address_space(1))) void*)(Ag + (size_t)(c * 64) * K + k0),
          (__attribute__((address_space(3))) void*)&Asm[(c * 64 + w * 16) * 32],
          16, 0, 0);
      __builtin_amdgcn_global_load_lds(
          (const __attribute__((address_space(1))) void*)(Bg + (size_t)(c * 64) * K + k0),
          (__attribute__((address_space(3))) void*)&Bsm[(c * 64 + w * 16) * 32],
          16, 0, 0);
    }
    __syncthreads();
    short8 af[4], bfv[4];
    #pragma unroll
    for (int i = 0; i < 4; i++) {
      af[i]  = *(const short8*)&Asm[(wm * 64 + i * 16 + (l & 15)) * 32 + (l >> 4) * 8];
      bfv[i] = *(const short8*)&Bsm[(wn * 64 + i * 16 + (l & 15)) * 32 + (l >> 4) * 8];
    }
    #pragma unroll
    for (int i = 0; i < 4; i++)
      #pragma unroll
      for (int j = 0; j < 4; j++)
        acc[i][j] = __builtin_amdgcn_mfma_f32_16x16x32_bf16(af[i], bfv[j], acc[i][j], 0, 0, 0);
    __syncthreads();
  }

  const int cl = l & 15, rq = l >> 4;
  #pragma unroll
  for (int i = 0; i < 4; i++) {
    int r0 = row0 + wm * 64 + i * 16 + rq * 4;
    #pragma unroll
    for (int j = 0; j < 4; j++) {
      int cc = col0 + wn * 64 + j * 16 + cl;
      #pragma unroll
      for (int r = 0; r < 4; r++)
        C[(size_t)(r0 + r) * N + cc] = acc[i][j][r];
    }
  }
}

// ------------- causal depthwise conv (K=4) + SiLU -------------
__global__ __launch_bounds__(256) void conv_silu(
    const float* __restrict__ qkv, const float* __restrict__ cw,
    float* __restrict__ mix) {
  size_t idx = (size_t)blockIdx.x * 256 + threadIdx.x;
  int c = (int)(idx % CONVD);
  size_t t = idx / CONVD;
  int s = (int)(t % SEQ);
  float w0 = cw[c * 4 + 0], w1 = cw[c * 4 + 1], w2 = cw[c * 4 + 2], w3 = cw[c * 4 + 3];
  const float* col = qkv + t * CONVD + c;
  float acc = w3 * col[0];
  if (s >= 1) acc += w2 * col[-(ptrdiff_t)CONVD];
  if (s >= 2) acc += w1 * col[-2 * (ptrdiff_t)CONVD];
  if (s >= 3) acc += w0 * col[-3 * (ptrdiff_t)CONVD];
  float sig = 1.f / (1.f + expf(-acc));
  mix[t * CONVD + c] = acc * sig;
}

// ------------- gates: write float2 {lg, beta} per (t, h) -------------
__global__ __launch_bounds__(256) void gates_kernel(
    const float* __restrict__ ba, const float* __restrict__ A_log,
    const float* __restrict__ dt_bias, float2* __restrict__ g2) {
  int idx = blockIdx.x * 256 + threadIdx.x;
  int h = idx & 31;
  size_t t = (size_t)(idx >> 5);
  float bv = ba[t * 64 + h];
  float av = ba[t * 64 + 32 + h];
  float beta = 1.f / (1.f + expf(-bv));
  float xx = av + dt_bias[h];
  float sp = (xx > 20.f) ? xx : log1pf(expf(xx));
  float lg = -expf(A_log[h]) * sp;
  g2[t * 32 + h] = make_float2(lg, beta);
}

// ------------- per-head L2 norm of q,k; writes bf16 copy -------------
__global__ __launch_bounds__(256) void l2norm_qk(
    const float* __restrict__ mix, ushort* __restrict__ kq) {
  int wid = (blockIdx.x * 256 + threadIdx.x) >> 6;
  int lane = threadIdx.x & 63;
  size_t t = (size_t)(wid >> 5);
  int hh = wid & 31;
  const float* p = mix + t * CONVD + (size_t)hh * DKH;
  float v0 = p[lane], v1 = p[lane + 64];
  float ss = v0 * v0 + v1 * v1;
  #pragma unroll
  for (int off = 32; off >= 1; off >>= 1) ss += __shfl_xor(ss, off, 64);
  float sc = rsqrtf(ss + EPSF);
  ushort* q = kq + t * 4096 + (size_t)hh * DKH;
  q[lane] = f2bf(v0 * sc);
  q[lane + 64] = f2bf(v1 * sc);
}

// ================= chunked delta-rule scan =================
// P1: per (b,h,chunk): Lg prefix, A = strict-lower beta_i e^{Lg_i-Lg_j}(k_i.k_j),
//     T = (I+A)^{-1}, M = incl-lower e^{Lg_i-Lg_j}(q_i.k_j). Reads bf16 kq.
__global__ __launch_bounds__(64) void chunk_prep(
    const ushort* __restrict__ kq, const float2* __restrict__ g2,
    float* __restrict__ Lgbuf, ushort* __restrict__ Tbuf,
    ushort* __restrict__ Mbuf) {
  const int blk = blockIdx.x;            // b*1024 + h*32 + ch
  const int ch = blk & 31;
  const int h  = (blk >> 5) & 31;
  const int b  = blk >> 10;
  const int kh = h >> 1;
  const int l  = threadIdx.x;
  const int fr = l & 15;
  const int fc8 = (l >> 4) * 8;
  const int cr = (l >> 4) * 4;

  __shared__ float sLg[64], sB[64];
  __shared__ float sA[64 * 65];
  __shared__ float sT[64 * 65];

  float2 gv = g2[((size_t)(b * SEQ + ch * 64 + l)) * 32 + h];
  float lg = gv.x;
  #pragma unroll
  for (int off = 1; off < 64; off <<= 1) {
    float n = __shfl_up(lg, off, 64);
    if (l >= off) lg += n;
  }
  sLg[l] = lg; sB[l] = gv.y;
  Lgbuf[(size_t)blk * 64 + l] = lg;
  __syncthreads();

  const ushort* qb = kq + ((size_t)(b * SEQ + ch * 64)) * 4096 + (size_t)kh * DKH;
  const ushort* kb = qb + 2048;

  floatx4 zero4 = {0.f, 0.f, 0.f, 0.f};
  floatx4 kk[4][4], qk[4][4];
  #pragma unroll
  for (int i = 0; i < 4; i++)
    #pragma unroll
    for (int j = 0; j < 4; j++) { kk[i][j] = zero4; qk[i][j] = zero4; }

  for (int ks = 0; ks < 4; ks++) {
    short8 kf[4], qf[4];
    #pragma unroll
    for (int m = 0; m < 4; m++) {
      kf[m] = *(const short8*)(kb + (size_t)(m * 16 + fr) * 4096 + fc8 + ks * 32);
      qf[m] = *(const short8*)(qb + (size_t)(m * 16 + fr) * 4096 + fc8 + ks * 32);
    }
    #pragma unroll
    for (int mt = 0; mt < 4; mt++)
      #pragma unroll
      for (int nt = 0; nt < 4; nt++) {
        kk[mt][nt] = __builtin_amdgcn_mfma_f32_16x16x32_bf16(kf[mt], kf[nt], kk[mt][nt], 0, 0, 0);
        qk[mt][nt] = __builtin_amdgcn_mfma_f32_16x16x32_bf16(qf[mt], kf[nt], qk[mt][nt], 0, 0, 0);
      }
  }

  const size_t tmbase = (size_t)blk * 4096;
  #pragma unroll
  for (int mt = 0; mt < 4; mt++)
    #pragma unroll
    for (int r = 0; r < 4; r++) {
      int i = mt * 16 + cr + r;
      float Li = sLg[i], Bi = sB[i];
      #pragma unroll
      for (int nt = 0; nt < 4; nt++) {
        int j = nt * 16 + fr;
        float dec = expf(Li - sLg[j]);
        sA[i * 65 + j] = (j < i) ? Bi * dec * kk[mt][nt][r] : 0.f;
        float mv = (j <= i) ? dec * qk[mt][nt][r] : 0.f;
        Mbuf[tmbase + (size_t)i * 64 + j] = f2bf(mv);
      }
    }
  __syncthreads();

  sT[0 * 65 + l] = (l == 0) ? 1.f : 0.f;
  for (int i = 1; i < 64; i++) {
    float acc = (l == i) ? 1.f : 0.f;
    for (int j = 0; j < i; j++)
      acc -= sA[i * 65 + j] * sT[j * 65 + l];
    sT[i * 65 + l] = acc;
  }
  for (int i = 0; i < 64; i++)
    Tbuf[tmbase + (size_t)i * 64 + l] = f2bf(sT[i * 65 + l]);
}

// P2: sequential over 32 chunks; state [128k,32v] in fp32 MFMA accumulators.
// v2: raw barriers (no vmcnt drain) + register prefetch (K/gates one chunk
// ahead, Q/T/M/V at chunk start) + K-tile in LDS for the (c) transpose read.
// Per-token scales applied to MFMA OUTPUT rows in f32 (P,O are row-linear).
struct KReg { short8 K[4]; float gLg, gB, gLgC; };

__global__ __launch_bounds__(256, 1) void chunk_scan(
    const float* __restrict__ mix, const ushort* __restrict__ kq,
    const float2* __restrict__ g2, const float* __restrict__ Lgbuf,
    const ushort* __restrict__ Tbuf, const ushort* __restrict__ Mbuf,
    float* __restrict__ core) {
  const int blk = blockIdx.x;
  const int vq = blk & 3;
  const int bh = blk >> 2;
  const int h = bh & 31;
  const int b = bh >> 5;
  const int kh = h >> 1;
  const int tid = threadIdx.x;
  const int w = tid >> 6;
  const int l = tid & 63;
  const int fr = l & 15;
  const int fc8 = (l >> 4) * 8;
  const int cr = (l >> 4) * 4;
  const int w16 = w * 16, w32 = w * 32;
  const int ia = w16 + fr;

  __shared__ __align__(16) ushort Kt[64][136];            // chunk K tile (bf16)
  __shared__ __align__(16) ushort STh[32][136], STl[32][136]; // S^T hi/lo
  __shared__ __align__(16) ushort DTh[32][72],  DTl[32][72];  // R^T / Delta^T hi/lo
  __shared__ float sKB[64], sQv[64], sKh[64], sBe[64], sLgC[1];

  for (int i = tid; i < 32 * 136; i += 256) { (&STh[0][0])[i] = 0; (&STl[0][0])[i] = 0; }

  floatx4 zero4 = {0.f, 0.f, 0.f, 0.f};
  floatx4 sacc[2][2] = {{zero4, zero4}, {zero4, zero4}};

  const size_t mixb = (size_t)b * SEQ * CONVD;
  const float* vb = mix + mixb + 2 * KEYD + (size_t)h * DVH + vq * 32;
  const ushort* kq_q = kq + (size_t)b * SEQ * 4096 + (size_t)kh * DKH;
  const ushort* kq_k = kq_q + 2048;
  const ushort* Tb = Tbuf + (size_t)bh * 32 * 4096;
  const ushort* Mb = Mbuf + (size_t)bh * 32 * 4096;
  const float* Lgb = Lgbuf + (size_t)bh * 2048;
  const float2* gp = g2 + (size_t)b * SEQ * 32 + h;
  float* cbase = core + (size_t)b * SEQ * VALD + (size_t)h * DVH + vq * 32;

  auto kpre = [&](KReg& R, int ch) {
    size_t ro = (size_t)(ch * 64 + ia) * 4096;
    #pragma unroll
    for (int ks = 0; ks < 4; ks++)
      R.K[ks] = *(const short8*)(kq_k + ro + fc8 + ks * 32);
    if (tid < 64) {
      R.gLg = Lgb[ch * 64 + tid];
      R.gLgC = Lgb[ch * 64 + 63];
      R.gB = gp[(size_t)(ch * 64 + tid) * 32].y;
    }
  };

  auto body = [&](KReg& cur, KReg& nxt, int ch) {
    const int tok0 = ch * 64;
    // --- stage gates + K tile (from prefetched regs) ---
    if (tid < 64) {
      float e = expf(cur.gLg);
      sKB[tid] = cur.gB * e;
      sQv[tid] = e;
      sKh[tid] = expf(cur.gLgC - cur.gLg);
      sBe[tid] = cur.gB;
      if (tid == 0) sLgC[0] = cur.gLgC;
    }
    #pragma unroll
    for (int ks = 0; ks < 4; ks++)
      *(short8*)&Kt[ia][fc8 + ks * 32] = cur.K[ks];
    // --- issue current-chunk operand loads (consumed 1-3 barriers later) ---
    short8 Qr[4], Tr[2], Mr[2];
    float Vr[8];
    {
      size_t ro = (size_t)(tok0 + ia) * 4096;
      #pragma unroll
      for (int ks = 0; ks < 4; ks++)
        Qr[ks] = *(const short8*)(kq_q + ro + fc8 + ks * 32);
      size_t tmb = (size_t)ch * 4096 + (size_t)ia * 64;
      #pragma unroll
      for (int ks = 0; ks < 2; ks++) {
        Tr[ks] = *(const short8*)(Tb + tmb + fc8 + ks * 32);
        Mr[ks] = *(const short8*)(Mb + tmb + fc8 + ks * 32);
      }
      #pragma unroll
      for (int nt = 0; nt < 2; nt++)
        #pragma unroll
        for (int r = 0; r < 4; r++)
          Vr[nt * 4 + r] = vb[(size_t)(tok0 + w16 + cr + r) * CONVD + nt * 16 + fr];
    }
    BAR();  // A: gates+Kt visible; prev-chunk ST writes ordered
    // --- prefetch next chunk K + gates (full-chunk lead) ---
    kpre(nxt, (ch + 1 < NCHUNK) ? ch + 1 : NCHUNK - 1);

    // ---- (a) Praw = K . S0 (raw K; row scale folded to epilogue) ----
    floatx4 p[2] = {zero4, zero4};
    #pragma unroll
    for (int ks = 0; ks < 4; ks++)
      #pragma unroll
      for (int nt = 0; nt < 2; nt++) {
        short8 bh_ = *(const short8*)&STh[nt * 16 + fr][fc8 + ks * 32];
        short8 bl_ = *(const short8*)&STl[nt * 16 + fr][fc8 + ks * 32];
        p[nt] = __builtin_amdgcn_mfma_f32_16x16x32_bf16(cur.K[ks], bh_, p[nt], 0, 0, 0);
        p[nt] = __builtin_amdgcn_mfma_f32_16x16x32_bf16(cur.K[ks], bl_, p[nt], 0, 0, 0);
      }
    // R = beta*v - sKB*Praw -> DT (hi/lo)
    #pragma unroll
    for (int nt = 0; nt < 2; nt++) {
      unsigned hv[4], lv[4];
      #pragma unroll
      for (int r = 0; r < 4; r++) {
        int i = w16 + cr + r;
        float Rv = sBe[i] * Vr[nt * 4 + r] - sKB[i] * p[nt][r];
        unsigned short hq = f2bf(Rv);
        hv[r] = hq; lv[r] = f2bf(Rv - bf2f(hq));
      }
      int v = nt * 16 + fr;
      *(uint2*)&DTh[v][w16 + cr] = make_uint2(hv[0] | (hv[1] << 16), hv[2] | (hv[3] << 16));
      *(uint2*)&DTl[v][w16 + cr] = make_uint2(lv[0] | (lv[1] << 16), lv[2] | (lv[3] << 16));
    }
    BAR();  // B

    // ---- (b) Delta = T . R ----
    floatx4 d[2] = {zero4, zero4};
    #pragma unroll
    for (int ks = 0; ks < 2; ks++)
      #pragma unroll
      for (int nt = 0; nt < 2; nt++) {
        short8 bh_ = *(const short8*)&DTh[nt * 16 + fr][fc8 + ks * 32];
        short8 bl_ = *(const short8*)&DTl[nt * 16 + fr][fc8 + ks * 32];
        d[nt] = __builtin_amdgcn_mfma_f32_16x16x32_bf16(Tr[ks], bh_, d[nt], 0, 0, 0);
        d[nt] = __builtin_amdgcn_mfma_f32_16x16x32_bf16(Tr[ks], bl_, d[nt], 0, 0, 0);
      }
    BAR();  // C
    #pragma unroll
    for (int nt = 0; nt < 2; nt++) {
      unsigned hv[4], lv[4];
      #pragma unroll
      for (int r = 0; r < 4; r++) {
        float dv = d[nt][r];
        unsigned short hq = f2bf(dv);
        hv[r] = hq; lv[r] = f2bf(dv - bf2f(hq));
      }
      int v = nt * 16 + fr;
      *(uint2*)&DTh[v][w16 + cr] = make_uint2(hv[0] | (hv[1] << 16), hv[2] | (hv[3] << 16));
      *(uint2*)&DTl[v][w16 + cr] = make_uint2(lv[0] | (lv[1] << 16), lv[2] | (lv[3] << 16));
    }
    BAR();  // D

    // ---- (d) O = sQv * (Q.S0) + M.Delta ----
    floatx4 oq[2] = {zero4, zero4}, od[2] = {zero4, zero4};
    #pragma unroll
    for (int ks = 0; ks < 4; ks++)
      #pragma unroll
      for (int nt = 0; nt < 2; nt++) {
        short8 bh_ = *(const short8*)&STh[nt * 16 + fr][fc8 + ks * 32];
        short8 bl_ = *(const short8*)&STl[nt * 16 + fr][fc8 + ks * 32];
        oq[nt] = __builtin_amdgcn_mfma_f32_16x16x32_bf16(Qr[ks], bh_, oq[nt], 0, 0, 0);
        oq[nt] = __builtin_amdgcn_mfma_f32_16x16x32_bf16(Qr[ks], bl_, oq[nt], 0, 0, 0);
      }
    #pragma unroll
    for (int ks = 0; ks < 2; ks++)
      #pragma unroll
      for (int nt = 0; nt < 2; nt++) {
        short8 bh_ = *(const short8*)&DTh[nt * 16 + fr][fc8 + ks * 32];
        short8 bl_ = *(const short8*)&DTl[nt * 16 + fr][fc8 + ks * 32];
        od[nt] = __builtin_amdgcn_mfma_f32_16x16x32_bf16(Mr[ks], bh_, od[nt], 0, 0, 0);
        od[nt] = __builtin_amdgcn_mfma_f32_16x16x32_bf16(Mr[ks], bl_, od[nt], 0, 0, 0);
      }
    #pragma unroll
    for (int nt = 0; nt < 2; nt++)
      #pragma unroll
      for (int r = 0; r < 4; r++) {
        int i = w16 + cr + r;
        cbase[(size_t)(tok0 + i) * VALD + nt * 16 + fr] = sQv[i] * oq[nt][r] + od[nt][r];
      }

    // ---- (c) S = e^LgC * S + (sKh K)^T . Delta ----
    float eL = expf(sLgC[0]);
    #pragma unroll
    for (int mt = 0; mt < 2; mt++)
      #pragma unroll
      for (int nt = 0; nt < 2; nt++)
        #pragma unroll
        for (int r = 0; r < 4; r++)
          sacc[mt][nt][r] *= eL;
    #pragma unroll
    for (int ks = 0; ks < 2; ks++) {
      short8 afm[2];
      #pragma unroll
      for (int mt = 0; mt < 2; mt++) {
        short8 a;
        #pragma unroll
        for (int jj = 0; jj < 8; jj++) {
          int tk = fc8 + ks * 32 + jj;
          float kv = bf2f(Kt[tk][w32 + mt * 16 + fr]);
          a[jj] = (short)f2bf(kv * sKh[tk]);
        }
        afm[mt] = a;
      }
      #pragma unroll
      for (int mt = 0; mt < 2; mt++)
        #pragma unroll
        for (int nt = 0; nt < 2; nt++) {
          short8 bh_ = *(const short8*)&DTh[nt * 16 + fr][fc8 + ks * 32];
          short8 bl_ = *(const short8*)&DTl[nt * 16 + fr][fc8 + ks * 32];
          sacc[mt][nt] = __builtin_amdgcn_mfma_f32_16x16x32_bf16(afm[mt], bh_, sacc[mt][nt], 0, 0, 0);
          sacc[mt][nt] = __builtin_amdgcn_mfma_f32_16x16x32_bf16(afm[mt], bl_, sacc[mt][nt], 0, 0, 0);
        }
    }
    BAR();  // E
    // ST <- sacc (hi/lo)
    #pragma unroll
    for (int mt = 0; mt < 2; mt++)
      #pragma unroll
      for (int nt = 0; nt < 2; nt++) {
        unsigned hv[4], lv[4];
        #pragma unroll
        for (int r = 0; r < 4; r++) {
          float sv = sacc[mt][nt][r];
          unsigned short hq = f2bf(sv);
          hv[r] = hq; lv[r] = f2bf(sv - bf2f(hq));
        }
        int v = nt * 16 + fr, k0 = w32 + mt * 16 + cr;
        *(uint2*)&STh[v][k0] = make_uint2(hv[0] | (hv[1] << 16), hv[2] | (hv[3] << 16));
        *(uint2*)&STl[v][k0] = make_uint2(lv[0] | (lv[1] << 16), lv[2] | (lv[3] << 16));
      }
  };

  KReg RA, RB;
  RA.gLg = RA.gB = RA.gLgC = 0.f;
  RB.gLg = RB.gB = RB.gLgC = 0.f;
  kpre(RA, 0);
  #pragma unroll 1
  for (int ch = 0; ch < NCHUNK; ch += 2) {
    body(RA, RB, ch);
    body(RB, RA, ch + 1);
  }
}

// ------------- RMSNorm(1+w) * silu(z) -> bf16 -------------
__global__ __launch_bounds__(256) void rmsnorm_silu(
    const float* __restrict__ core, const float* __restrict__ zbuf,
    const float* __restrict__ norm_w, ushort* __restrict__ out_bf) {
  int t = blockIdx.x;
  int tid = threadIdx.x;
  const float* row = core + (size_t)t * VALD;
  const float* zrow = zbuf + (size_t)t * VALD;
  ushort* orow = out_bf + (size_t)t * VALD;
  float vals[16];
  float ss = 0.f;
  #pragma unroll
  for (int i = 0; i < 16; i++) { float x = row[tid + i * 256]; vals[i] = x; ss += x * x; }
  #pragma unroll
  for (int off = 32; off >= 1; off >>= 1) ss += __shfl_xor(ss, off, 64);
  __shared__ float red[4];
  if ((tid & 63) == 0) red[tid >> 6] = ss;
  __syncthreads();
  float tot = red[0] + red[1] + red[2] + red[3];
  float scale = rsqrtf(tot * (1.f / VALD) + EPSF);
  #pragma unroll
  for (int i = 0; i < 16; i++) {
    int c = tid + i * 256;
    float z = zrow[c];
    float sz = z / (1.f + expf(-z));
    orow[c] = f2bf(vals[i] * scale * (1.f + norm_w[c]) * sz);
  }
}

extern "C" void kernel_launch(void* const* d_in, const int* in_sizes, int n_in,
                              void* d_out, int out_size, void* d_ws, size_t ws_size,
                              hipStream_t stream) {
  const float* x       = (const float*)d_in[0];
  const float* W_qkvz  = (const float*)d_in[1];
  const float* W_ba    = (const float*)d_in[2];
  const float* conv_w  = (const float*)d_in[3];
  const float* dt_bias = (const float*)d_in[4];
  const float* A_log   = (const float*)d_in[5];
  const float* norm_w  = (const float*)d_in[6];
  const float* W_out   = (const float*)d_in[7];
  float* out = (float*)d_out;

  // workspace layout (floats), total 84,410,368 fl = 337.6 MB
  float* ws = (float*)d_ws;
  float* A  = ws;                         // 33,554,432 fl
  float* Bp = A + (size_t)33554432;       // 33,554,432 fl
  float* Cp = Bp + (size_t)33554432;      // 16,777,216 fl
  float* ba = Cp + (size_t)16777216;      //    262,144 fl
  float* g2 = ba + (size_t)262144;        //    262,144 fl (float2[TOK*32])

  ushort* x_bf    = (ushort*)Cp;
  ushort* Wqkv_bf = (ushort*)Bp;
  float*  zb      = A;                    // A[0 .. 16,777,216)
  ushort* core_bf = (ushort*)(A + (size_t)16777216);   // after scan only (over Tbuf)
  ushort* Wz_bf   = (ushort*)(A + (size_t)25165824);   // before l2norm only
  ushort* Wo_bf   = (ushort*)Bp;
  float*  mix     = Bp;
  float*  core    = Cp;
  // chunked-scan buffers in A-upper:
  ushort* Tbuf    = (ushort*)(A + (size_t)16777216);   // 4,194,304 fl
  ushort* Mbuf    = (ushort*)(A + (size_t)20971520);   // 4,194,304 fl
  ushort* kq_bf   = (ushort*)(A + (size_t)25165824);   // 8,388,608 fl (32 MB)
  float*  Lgbuf   = ba;                                // ba dead after gates_kernel

  // 1) casts for qkv projection
  cast_bf16<<<(TOK * HS / 4 + 255) / 256, 256, 0, stream>>>((const float4*)x, (ushort4*)x_bf, TOK * HS / 4);
  cast_bf16<<<(CONVD * HS / 4 + 255) / 256, 256, 0, stream>>>((const float4*)W_qkvz, (ushort4*)Wqkv_bf, CONVD * HS / 4);
  // 2) qkv projection (bf16 MFMA): [TOK, 8192]
  gemm_bf16_nt<<<dim3(CONVD / 128, TOK / 128), 256, 0, stream>>>(x_bf, Wqkv_bf, A, TOK, CONVD, HS);
  // 3) ba projection (fp32, tiny)
  gemm_nt<<<dim3(1, TOK / 64), 256, 0, stream>>>(x, W_ba, ba, TOK, 64, HS);
  // 4) conv + silu: A -> mix
  conv_silu<<<(int)(((size_t)TOK * CONVD) / 256), 256, 0, stream>>>(A, conv_w, mix);
  // 5) z projection: cast z-rows of W_qkvz, GEMM into A
  cast_bf16<<<(VALD * HS / 4 + 255) / 256, 256, 0, stream>>>(
      (const float4*)(W_qkvz + (size_t)(2 * KEYD + VALD) * HS), (ushort4*)Wz_bf, VALD * HS / 4);
  gemm_bf16_nt<<<dim3(VALD / 128, TOK / 128), 256, 0, stream>>>(x_bf, Wz_bf, zb, TOK, VALD, HS);
  // 6) gates -> float2 {lg, beta}
  gates_kernel<<<TOK * NVH / 256, 256, 0, stream>>>(ba, A_log, dt_bias, (float2*)g2);
  // 7) l2 norm q,k -> bf16 kq buffer (fp32 q/k in mix become dead)
  l2norm_qk<<<TOK * 32 / 4, 256, 0, stream>>>(mix, kq_bf);
  // 8) chunked delta-rule scan
  chunk_prep<<<NBATCH * NVH * NCHUNK, 64, 0, stream>>>(kq_bf, (const float2*)g2, Lgbuf, Tbuf, Mbuf);
  chunk_scan<<<NBATCH * NVH * 4, 256, 0, stream>>>(mix, kq_bf, (const float2*)g2, Lgbuf, Tbuf, Mbuf, core);
  // 9) rmsnorm * silu(z) -> bf16
  rmsnorm_silu<<<TOK, 256, 0, stream>>>(core, zb, norm_w, core_bf);
  // 10) output projection
  cast_bf16<<<(HS * VALD / 4 + 255) / 256, 256, 0, stream>>>((const float4*)W_out, (ushort4*)Wo_bf, HS * VALD / 4);
  gemm_bf16_nt<<<dim3(HS / 128, TOK / 128), 256, 0, stream>>>(core_bf, Wo_bf, out, TOK, HS, VALD);
}

// Round 6
// 1036.887 us; speedup vs baseline: 2.1691x; 1.0662x over previous
//
#include <hip/hip_runtime.h>
#include <hip/hip_bf16.h>
#include <math.h>

#define TOK    4096   // B*S
#define HS     2048
#define CONVD  8192
#define KEYD   2048
#define VALD   4096
#define NKH    16
#define NVH    32
#define DKH    128
#define DVH    128
#define SEQ    2048
#define NBATCH 2
#define EPSF   1e-6f
#define CHUNK  64
#define NCHUNK 32

typedef __attribute__((ext_vector_type(8))) short short8;
typedef __attribute__((ext_vector_type(4))) float floatx4;

static __device__ __forceinline__ unsigned short f2bf(float x) {
  union { float f; unsigned u; } c; c.f = x;
  unsigned r = (c.u + 0x7FFF + ((c.u >> 16) & 1)) >> 16;
  return (unsigned short)r;
}
static __device__ __forceinline__ float bf2f(unsigned short u) {
  union { unsigned u; float f; } c; c.u = ((unsigned)u) << 16;
  return c.f;
}

// raw workgroup barrier: orders LDS (lgkmcnt) but does NOT drain vmcnt
#define BAR() do { \
  __builtin_amdgcn_sched_barrier(0); \
  asm volatile("s_waitcnt lgkmcnt(0)" ::: "memory"); \
  __builtin_amdgcn_s_barrier(); \
  __builtin_amdgcn_sched_barrier(0); \
} while (0)

// ---------------- fp32 GEMM (tiny ba projection only) ----------------
__global__ __launch_bounds__(256) void gemm_nt(
    const float* __restrict__ A, const float* __restrict__ B,
    float* __restrict__ C, int M, int N, int K) {
  __shared__ float As[16][68];
  __shared__ float Bs[16][68];
  const int tx = threadIdx.x & 15;
  const int ty = threadIdx.x >> 4;
  const int row0 = blockIdx.y * 64;
  const int col0 = blockIdx.x * 64;
  const int lr = threadIdx.x >> 2;
  const int lc = (threadIdx.x & 3) * 4;
  float acc[4][4] = {};
  for (int k0 = 0; k0 < K; k0 += 16) {
    float4 av = *(const float4*)&A[(size_t)(row0 + lr) * K + (k0 + lc)];
    float4 bv = *(const float4*)&B[(size_t)(col0 + lr) * K + (k0 + lc)];
    As[lc + 0][lr] = av.x; As[lc + 1][lr] = av.y;
    As[lc + 2][lr] = av.z; As[lc + 3][lr] = av.w;
    Bs[lc + 0][lr] = bv.x; Bs[lc + 1][lr] = bv.y;
    Bs[lc + 2][lr] = bv.z; Bs[lc + 3][lr] = bv.w;
    __syncthreads();
    #pragma unroll
    for (int kk = 0; kk < 16; kk++) {
      float a[4], b[4];
      #pragma unroll
      for (int i = 0; i < 4; i++) a[i] = As[kk][ty * 4 + i];
      #pragma unroll
      for (int i = 0; i < 4; i++) b[i] = Bs[kk][tx * 4 + i];
      #pragma unroll
      for (int i = 0; i < 4; i++)
        #pragma unroll
        for (int j = 0; j < 4; j++)
          acc[i][j] += a[i] * b[j];
    }
    __syncthreads();
  }
  #pragma unroll
  for (int i = 0; i < 4; i++) {
    float4 v = make_float4(acc[i][0], acc[i][1], acc[i][2], acc[i][3]);
    *(float4*)&C[(size_t)(row0 + ty * 4 + i) * N + (col0 + tx * 4)] = v;
  }
}

// ---------------- fp32 -> bf16 cast ----------------
__global__ __launch_bounds__(256) void cast_bf16(
    const float4* __restrict__ src, ushort4* __restrict__ dst, int n4) {
  int i = blockIdx.x * 256 + threadIdx.x;
  if (i < n4) {
    float4 v = src[i];
    ushort4 o;
    o.x = f2bf(v.x); o.y = f2bf(v.y); o.z = f2bf(v.z); o.w = f2bf(v.w);
    dst[i] = o;
  }
}

// ======== 256x256 8-phase bf16 GEMM: C[M,N] = A[M,K]*B[N,K]^T ========
// 512 thr = 8 waves (2M x 4N); BK=64; dbuf LDS 128KB; XOR-swizzled LDS
// (unit ^= row&7, pre-swizzled global source + swizzled ds_read).
// Stagger: P1 stages A-hi(t+1), P2 B-hi(t+1), P3 B-lo(t+2), P4 A-lo(t+2).
// ONE counted vmcnt(4) per K-tile before the tile-end barrier.
#define GBM 256
#define GBK 64

#define STAGE(DST, SRC, BUF, HALF, KT) do { \
  __builtin_amdgcn_global_load_lds( \
      (const __attribute__((address_space(1))) void*)((SRC) + (size_t)((HALF) * 128) * K + (size_t)(KT) * 64), \
      (__attribute__((address_space(3))) void*)&DST[BUF][((HALF) * 128 + wrow) * GBK], 16, 0, 0); \
  __builtin_amdgcn_global_load_lds( \
      (const __attribute__((address_space(1))) void*)((SRC) + (size_t)((HALF) * 128 + 64) * K + (size_t)(KT) * 64), \
      (__attribute__((address_space(3))) void*)&DST[BUF][((HALF) * 128 + 64 + wrow) * GBK], 16, 0, 0); \
} while (0)

__global__ __launch_bounds__(512, 2) void gemm256(
    const ushort* __restrict__ A, const ushort* __restrict__ B,
    float* __restrict__ C, int M, int N, int K) {
  __shared__ ushort As[2][GBM * GBK];   // 64 KB
  __shared__ ushort Bs[2][GBM * GBK];   // 64 KB

  const int tid = threadIdx.x;
  const int w = tid >> 6, l = tid & 63;
  const int wm = w >> 2, wn = w & 3;          // 2 x 4 wave grid
  const int row0 = blockIdx.y * GBM, col0 = blockIdx.x * GBM;
  const int nt = K >> 6;

  // staging addressing (pre-swizzled global source)
  const int srow = tid >> 3;                  // 0..63
  const int sunit = (tid & 7) ^ (srow & 7);
  const int wrow = w * 8;
  const ushort* Ag = A + (size_t)(row0 + srow) * K + sunit * 8;
  const ushort* Bg = B + (size_t)(col0 + srow) * K + sunit * 8;

  // ds_read addressing (swizzled)
  const int aoff = (wm * 128 + (l & 15)) * GBK;
  const int boff = (wn * 64 + (l & 15)) * GBK;
  const int u0 = (((l >> 4) ^ (l & 7)) * 8);
  const int u1 = u0 ^ 32;

  floatx4 acc[8][4];
  #pragma unroll
  for (int i = 0; i < 8; i++)
    #pragma unroll
    for (int j = 0; j < 4; j++)
      acc[i][j] = (floatx4){0.f, 0.f, 0.f, 0.f};

  // prologue (issue order mimics steady state)
  STAGE(Bs, Bg, 0, 0, 0);
  STAGE(As, Ag, 0, 0, 0);
  STAGE(As, Ag, 0, 1, 0);
  STAGE(Bs, Bg, 0, 1, 0);
  STAGE(Bs, Bg, 1, 0, 1);
  STAGE(As, Ag, 1, 0, 1);
  asm volatile("s_waitcnt vmcnt(4)" ::: "memory");
  __builtin_amdgcn_sched_barrier(0);
  __builtin_amdgcn_s_barrier();
  __builtin_amdgcn_sched_barrier(0);

  short8 rA[4][2], rB0[2][2], rB1[2][2];

  #pragma unroll 1
  for (int t = 0; t < nt; ++t) {
    const int buf = t & 1, nbuf = buf ^ 1;
    const ushort* Ab = &As[buf][0];
    const ushort* Bb = &Bs[buf][0];

    // ---------- P1: read A0 + B0; MFMA q(0,0); stage A-hi(t+1) ----------
    #pragma unroll
    for (int fm = 0; fm < 4; fm++) {
      rA[fm][0] = *(const short8*)&Ab[aoff + (fm * 16) * GBK + u0];
      rA[fm][1] = *(const short8*)&Ab[aoff + (fm * 16) * GBK + u1];
    }
    #pragma unroll
    for (int fn = 0; fn < 2; fn++) {
      rB0[fn][0] = *(const short8*)&Bb[boff + (fn * 16) * GBK + u0];
      rB0[fn][1] = *(const short8*)&Bb[boff + (fn * 16) * GBK + u1];
    }
    if (t + 1 < nt) STAGE(As, Ag, nbuf, 1, t + 1);
    __builtin_amdgcn_sched_barrier(0);
    __builtin_amdgcn_s_barrier();
    asm volatile("s_waitcnt lgkmcnt(0)" ::: "memory");
    __builtin_amdgcn_sched_barrier(0);
    __builtin_amdgcn_s_setprio(1);
    #pragma unroll
    for (int ks = 0; ks < 2; ks++)
      #pragma unroll
      for (int fm = 0; fm < 4; fm++)
        #pragma unroll
        for (int fn = 0; fn < 2; fn++)
          acc[fm][fn] = __builtin_amdgcn_mfma_f32_16x16x32_bf16(rA[fm][ks], rB0[fn][ks], acc[fm][fn], 0, 0, 0);
    __builtin_amdgcn_s_setprio(0);
    __builtin_amdgcn_sched_barrier(0);
    __builtin_amdgcn_s_barrier();
    __builtin_amdgcn_sched_barrier(0);

    // ---------- P2: read B1; MFMA q(0,1); stage B-hi(t+1) ----------
    #pragma unroll
    for (int fn = 0; fn < 2; fn++) {
      rB1[fn][0] = *(const short8*)&Bb[boff + (32 + fn * 16) * GBK + u0];
      rB1[fn][1] = *(const short8*)&Bb[boff + (32 + fn * 16) * GBK + u1];
    }
    if (t + 1 < nt) STAGE(Bs, Bg, nbuf, 1, t + 1);
    __builtin_amdgcn_sched_barrier(0);
    __builtin_amdgcn_s_barrier();
    asm volatile("s_waitcnt lgkmcnt(0)" ::: "memory");
    __builtin_amdgcn_sched_barrier(0);
    __builtin_amdgcn_s_setprio(1);
    #pragma unroll
    for (int ks = 0; ks < 2; ks++)
      #pragma unroll
      for (int fm = 0; fm < 4; fm++)
        #pragma unroll
        for (int fn = 0; fn < 2; fn++)
          acc[fm][2 + fn] = __builtin_amdgcn_mfma_f32_16x16x32_bf16(rA[fm][ks], rB1[fn][ks], acc[fm][2 + fn], 0, 0, 0);
    __builtin_amdgcn_s_setprio(0);
    __builtin_amdgcn_sched_barrier(0);
    __builtin_amdgcn_s_barrier();
    __builtin_amdgcn_sched_barrier(0);

    // ---------- P3: read A1; MFMA q(1,1); stage B-lo(t+2) ----------
    #pragma unroll
    for (int fm = 0; fm < 4; fm++) {
      rA[fm][0] = *(const short8*)&Ab[aoff + (64 + fm * 16) * GBK + u0];
      rA[fm][1] = *(const short8*)&Ab[aoff + (64 + fm * 16) * GBK + u1];
    }
    if (t + 2 < nt) STAGE(Bs, Bg, buf, 0, t + 2);
    __builtin_amdgcn_sched_barrier(0);
    __builtin_amdgcn_s_barrier();
    asm volatile("s_waitcnt lgkmcnt(0)" ::: "memory");
    __builtin_amdgcn_sched_barrier(0);
    __builtin_amdgcn_s_setprio(1);
    #pragma unroll
    for (int ks = 0; ks < 2; ks++)
      #pragma unroll
      for (int fm = 0; fm < 4; fm++)
        #pragma unroll
        for (int fn = 0; fn < 2; fn++)
          acc[4 + fm][2 + fn] = __builtin_amdgcn_mfma_f32_16x16x32_bf16(rA[fm][ks], rB1[fn][ks], acc[4 + fm][2 + fn], 0, 0, 0);
    __builtin_amdgcn_s_setprio(0);
    __builtin_amdgcn_sched_barrier(0);
    __builtin_amdgcn_s_barrier();
    __builtin_amdgcn_sched_barrier(0);

    // ---------- P4: MFMA q(1,0) (rA from P3, rB0 held); stage A-lo(t+2) ----------
    if (t + 2 < nt) STAGE(As, Ag, buf, 0, t + 2);
    __builtin_amdgcn_sched_barrier(0);
    __builtin_amdgcn_s_barrier();
    __builtin_amdgcn_sched_barrier(0);
    __builtin_amdgcn_s_setprio(1);
    #pragma unroll
    for (int ks = 0; ks < 2; ks++)
      #pragma unroll
      for (int fm = 0; fm < 4; fm++)
        #pragma unroll
        for (int fn = 0; fn < 2; fn++)
          acc[4 + fm][fn] = __builtin_amdgcn_mfma_f32_16x16x32_bf16(rA[fm][ks], rB0[fn][ks], acc[4 + fm][fn], 0, 0, 0);
    __builtin_amdgcn_s_setprio(0);
    if (t + 2 < nt) {
      asm volatile("s_waitcnt vmcnt(4)" ::: "memory");
    } else if (t + 1 < nt) {
      asm volatile("s_waitcnt vmcnt(0)" ::: "memory");
    }
    __builtin_amdgcn_sched_barrier(0);
    __builtin_amdgcn_s_barrier();
    __builtin_amdgcn_sched_barrier(0);
  }

  const int cl = l & 15, rq = l >> 4;
  #pragma unroll
  for (int i = 0; i < 8; i++) {
    int r0 = row0 + wm * 128 + (i >> 2) * 64 + (i & 3) * 16 + rq * 4;
    #pragma unroll
    for (int j = 0; j < 4; j++) {
      int cc = col0 + wn * 64 + (j >> 1) * 32 + (j & 1) * 16 + cl;
      #pragma unroll
      for (int r = 0; r < 4; r++)
        C[(size_t)(r0 + r) * N + cc] = acc[i][j][r];
    }
  }
}

// ------------- causal depthwise conv (K=4) + SiLU -------------
__global__ __launch_bounds__(256) void conv_silu(
    const float* __restrict__ qkv, const float* __restrict__ cw,
    float* __restrict__ mix) {
  size_t idx = (size_t)blockIdx.x * 256 + threadIdx.x;
  int c = (int)(idx % CONVD);
  size_t t = idx / CONVD;
  int s = (int)(t % SEQ);
  float w0 = cw[c * 4 + 0], w1 = cw[c * 4 + 1], w2 = cw[c * 4 + 2], w3 = cw[c * 4 + 3];
  const float* col = qkv + t * CONVD + c;
  float acc = w3 * col[0];
  if (s >= 1) acc += w2 * col[-(ptrdiff_t)CONVD];
  if (s >= 2) acc += w1 * col[-2 * (ptrdiff_t)CONVD];
  if (s >= 3) acc += w0 * col[-3 * (ptrdiff_t)CONVD];
  float sig = 1.f / (1.f + expf(-acc));
  mix[t * CONVD + c] = acc * sig;
}

// ------------- gates: write float2 {lg, beta} per (t, h) -------------
__global__ __launch_bounds__(256) void gates_kernel(
    const float* __restrict__ ba, const float* __restrict__ A_log,
    const float* __restrict__ dt_bias, float2* __restrict__ g2) {
  int idx = blockIdx.x * 256 + threadIdx.x;
  int h = idx & 31;
  size_t t = (size_t)(idx >> 5);
  float bv = ba[t * 64 + h];
  float av = ba[t * 64 + 32 + h];
  float beta = 1.f / (1.f + expf(-bv));
  float xx = av + dt_bias[h];
  float sp = (xx > 20.f) ? xx : log1pf(expf(xx));
  float lg = -expf(A_log[h]) * sp;
  g2[t * 32 + h] = make_float2(lg, beta);
}

// ------------- per-head L2 norm of q,k; writes bf16 copy -------------
__global__ __launch_bounds__(256) void l2norm_qk(
    const float* __restrict__ mix, ushort* __restrict__ kq) {
  int wid = (blockIdx.x * 256 + threadIdx.x) >> 6;
  int lane = threadIdx.x & 63;
  size_t t = (size_t)(wid >> 5);
  int hh = wid & 31;
  const float* p = mix + t * CONVD + (size_t)hh * DKH;
  float v0 = p[lane], v1 = p[lane + 64];
  float ss = v0 * v0 + v1 * v1;
  #pragma unroll
  for (int off = 32; off >= 1; off >>= 1) ss += __shfl_xor(ss, off, 64);
  float sc = rsqrtf(ss + EPSF);
  ushort* q = kq + t * 4096 + (size_t)hh * DKH;
  q[lane] = f2bf(v0 * sc);
  q[lane + 64] = f2bf(v1 * sc);
}

// ================= chunked delta-rule scan =================
__global__ __launch_bounds__(64) void chunk_prep(
    const ushort* __restrict__ kq, const float2* __restrict__ g2,
    float* __restrict__ Lgbuf, ushort* __restrict__ Tbuf,
    ushort* __restrict__ Mbuf) {
  const int blk = blockIdx.x;            // b*1024 + h*32 + ch
  const int ch = blk & 31;
  const int h  = (blk >> 5) & 31;
  const int b  = blk >> 10;
  const int kh = h >> 1;
  const int l  = threadIdx.x;
  const int fr = l & 15;
  const int fc8 = (l >> 4) * 8;
  const int cr = (l >> 4) * 4;

  __shared__ float sLg[64], sB[64];
  __shared__ float sA[64 * 65];
  __shared__ float sT[64 * 65];

  float2 gv = g2[((size_t)(b * SEQ + ch * 64 + l)) * 32 + h];
  float lg = gv.x;
  #pragma unroll
  for (int off = 1; off < 64; off <<= 1) {
    float n = __shfl_up(lg, off, 64);
    if (l >= off) lg += n;
  }
  sLg[l] = lg; sB[l] = gv.y;
  Lgbuf[(size_t)blk * 64 + l] = lg;
  __syncthreads();

  const ushort* qb = kq + ((size_t)(b * SEQ + ch * 64)) * 4096 + (size_t)kh * DKH;
  const ushort* kb = qb + 2048;

  floatx4 zero4 = {0.f, 0.f, 0.f, 0.f};
  floatx4 kk[4][4], qk[4][4];
  #pragma unroll
  for (int i = 0; i < 4; i++)
    #pragma unroll
    for (int j = 0; j < 4; j++) { kk[i][j] = zero4; qk[i][j] = zero4; }

  for (int ks = 0; ks < 4; ks++) {
    short8 kf[4], qf[4];
    #pragma unroll
    for (int m = 0; m < 4; m++) {
      kf[m] = *(const short8*)(kb + (size_t)(m * 16 + fr) * 4096 + fc8 + ks * 32);
      qf[m] = *(const short8*)(qb + (size_t)(m * 16 + fr) * 4096 + fc8 + ks * 32);
    }
    #pragma unroll
    for (int mt = 0; mt < 4; mt++)
      #pragma unroll
      for (int nt = 0; nt < 4; nt++) {
        kk[mt][nt] = __builtin_amdgcn_mfma_f32_16x16x32_bf16(kf[mt], kf[nt], kk[mt][nt], 0, 0, 0);
        qk[mt][nt] = __builtin_amdgcn_mfma_f32_16x16x32_bf16(qf[mt], kf[nt], qk[mt][nt], 0, 0, 0);
      }
  }

  const size_t tmbase = (size_t)blk * 4096;
  #pragma unroll
  for (int mt = 0; mt < 4; mt++)
    #pragma unroll
    for (int r = 0; r < 4; r++) {
      int i = mt * 16 + cr + r;
      float Li = sLg[i], Bi = sB[i];
      #pragma unroll
      for (int nt = 0; nt < 4; nt++) {
        int j = nt * 16 + fr;
        float dec = expf(Li - sLg[j]);
        sA[i * 65 + j] = (j < i) ? Bi * dec * kk[mt][nt][r] : 0.f;
        float mv = (j <= i) ? dec * qk[mt][nt][r] : 0.f;
        Mbuf[tmbase + (size_t)i * 64 + j] = f2bf(mv);
      }
    }
  __syncthreads();

  sT[0 * 65 + l] = (l == 0) ? 1.f : 0.f;
  for (int i = 1; i < 64; i++) {
    float acc = (l == i) ? 1.f : 0.f;
    for (int j = 0; j < i; j++)
      acc -= sA[i * 65 + j] * sT[j * 65 + l];
    sT[i * 65 + l] = acc;
  }
  for (int i = 0; i < 64; i++)
    Tbuf[tmbase + (size_t)i * 64 + l] = f2bf(sT[i * 65 + l]);
}

// P2: sequential over 32 chunks; state [128k,32v] in fp32 MFMA accumulators.
struct KReg { short8 K[4]; float gLg, gB, gLgC; };

__global__ __launch_bounds__(256, 1) void chunk_scan(
    const float* __restrict__ mix, const ushort* __restrict__ kq,
    const float2* __restrict__ g2, const float* __restrict__ Lgbuf,
    const ushort* __restrict__ Tbuf, const ushort* __restrict__ Mbuf,
    float* __restrict__ core) {
  const int blk = blockIdx.x;
  const int vq = blk & 3;
  const int bh = blk >> 2;
  const int h = bh & 31;
  const int b = bh >> 5;
  const int kh = h >> 1;
  const int tid = threadIdx.x;
  const int w = tid >> 6;
  const int l = tid & 63;
  const int fr = l & 15;
  const int fc8 = (l >> 4) * 8;
  const int cr = (l >> 4) * 4;
  const int w16 = w * 16, w32 = w * 32;
  const int ia = w16 + fr;

  __shared__ __align__(16) ushort Kt[64][136];
  __shared__ __align__(16) ushort STh[32][136], STl[32][136];
  __shared__ __align__(16) ushort DTh[32][72],  DTl[32][72];
  __shared__ float sKB[64], sQv[64], sKh[64], sBe[64], sLgC[1];

  for (int i = tid; i < 32 * 136; i += 256) { (&STh[0][0])[i] = 0; (&STl[0][0])[i] = 0; }

  floatx4 zero4 = {0.f, 0.f, 0.f, 0.f};
  floatx4 sacc[2][2] = {{zero4, zero4}, {zero4, zero4}};

  const size_t mixb = (size_t)b * SEQ * CONVD;
  const float* vb = mix + mixb + 2 * KEYD + (size_t)h * DVH + vq * 32;
  const ushort* kq_q = kq + (size_t)b * SEQ * 4096 + (size_t)kh * DKH;
  const ushort* kq_k = kq_q + 2048;
  const ushort* Tb = Tbuf + (size_t)bh * 32 * 4096;
  const ushort* Mb = Mbuf + (size_t)bh * 32 * 4096;
  const float* Lgb = Lgbuf + (size_t)bh * 2048;
  const float2* gp = g2 + (size_t)b * SEQ * 32 + h;
  float* cbase = core + (size_t)b * SEQ * VALD + (size_t)h * DVH + vq * 32;

  auto kpre = [&](KReg& R, int ch) {
    size_t ro = (size_t)(ch * 64 + ia) * 4096;
    #pragma unroll
    for (int ks = 0; ks < 4; ks++)
      R.K[ks] = *(const short8*)(kq_k + ro + fc8 + ks * 32);
    if (tid < 64) {
      R.gLg = Lgb[ch * 64 + tid];
      R.gLgC = Lgb[ch * 64 + 63];
      R.gB = gp[(size_t)(ch * 64 + tid) * 32].y;
    }
  };

  auto body = [&](KReg& cur, KReg& nxt, int ch) {
    const int tok0 = ch * 64;
    if (tid < 64) {
      float e = expf(cur.gLg);
      sKB[tid] = cur.gB * e;
      sQv[tid] = e;
      sKh[tid] = expf(cur.gLgC - cur.gLg);
      sBe[tid] = cur.gB;
      if (tid == 0) sLgC[0] = cur.gLgC;
    }
    #pragma unroll
    for (int ks = 0; ks < 4; ks++)
      *(short8*)&Kt[ia][fc8 + ks * 32] = cur.K[ks];
    short8 Qr[4], Tr[2], Mr[2];
    float Vr[8];
    {
      size_t ro = (size_t)(tok0 + ia) * 4096;
      #pragma unroll
      for (int ks = 0; ks < 4; ks++)
        Qr[ks] = *(const short8*)(kq_q + ro + fc8 + ks * 32);
      size_t tmb = (size_t)ch * 4096 + (size_t)ia * 64;
      #pragma unroll
      for (int ks = 0; ks < 2; ks++) {
        Tr[ks] = *(const short8*)(Tb + tmb + fc8 + ks * 32);
        Mr[ks] = *(const short8*)(Mb + tmb + fc8 + ks * 32);
      }
      #pragma unroll
      for (int nt = 0; nt < 2; nt++)
        #pragma unroll
        for (int r = 0; r < 4; r++)
          Vr[nt * 4 + r] = vb[(size_t)(tok0 + w16 + cr + r) * CONVD + nt * 16 + fr];
    }
    BAR();  // A
    kpre(nxt, (ch + 1 < NCHUNK) ? ch + 1 : NCHUNK - 1);

    floatx4 p[2] = {zero4, zero4};
    #pragma unroll
    for (int ks = 0; ks < 4; ks++)
      #pragma unroll
      for (int nt = 0; nt < 2; nt++) {
        short8 bh_ = *(const short8*)&STh[nt * 16 + fr][fc8 + ks * 32];
        short8 bl_ = *(const short8*)&STl[nt * 16 + fr][fc8 + ks * 32];
        p[nt] = __builtin_amdgcn_mfma_f32_16x16x32_bf16(cur.K[ks], bh_, p[nt], 0, 0, 0);
        p[nt] = __builtin_amdgcn_mfma_f32_16x16x32_bf16(cur.K[ks], bl_, p[nt], 0, 0, 0);
      }
    #pragma unroll
    for (int nt = 0; nt < 2; nt++) {
      unsigned hv[4], lv[4];
      #pragma unroll
      for (int r = 0; r < 4; r++) {
        int i = w16 + cr + r;
        float Rv = sBe[i] * Vr[nt * 4 + r] - sKB[i] * p[nt][r];
        unsigned short hq = f2bf(Rv);
        hv[r] = hq; lv[r] = f2bf(Rv - bf2f(hq));
      }
      int v = nt * 16 + fr;
      *(uint2*)&DTh[v][w16 + cr] = make_uint2(hv[0] | (hv[1] << 16), hv[2] | (hv[3] << 16));
      *(uint2*)&DTl[v][w16 + cr] = make_uint2(lv[0] | (lv[1] << 16), lv[2] | (lv[3] << 16));
    }
    BAR();  // B

    floatx4 d[2] = {zero4, zero4};
    #pragma unroll
    for (int ks = 0; ks < 2; ks++)
      #pragma unroll
      for (int nt = 0; nt < 2; nt++) {
        short8 bh_ = *(const short8*)&DTh[nt * 16 + fr][fc8 + ks * 32];
        short8 bl_ = *(const short8*)&DTl[nt * 16 + fr][fc8 + ks * 32];
        d[nt] = __builtin_amdgcn_mfma_f32_16x16x32_bf16(Tr[ks], bh_, d[nt], 0, 0, 0);
        d[nt] = __builtin_amdgcn_mfma_f32_16x16x32_bf16(Tr[ks], bl_, d[nt], 0, 0, 0);
      }
    BAR();  // C
    #pragma unroll
    for (int nt = 0; nt < 2; nt++) {
      unsigned hv[4], lv[4];
      #pragma unroll
      for (int r = 0; r < 4; r++) {
        float dv = d[nt][r];
        unsigned short hq = f2bf(dv);
        hv[r] = hq; lv[r] = f2bf(dv - bf2f(hq));
      }
      int v = nt * 16 + fr;
      *(uint2*)&DTh[v][w16 + cr] = make_uint2(hv[0] | (hv[1] << 16), hv[2] | (hv[3] << 16));
      *(uint2*)&DTl[v][w16 + cr] = make_uint2(lv[0] | (lv[1] << 16), lv[2] | (lv[3] << 16));
    }
    BAR();  // D

    floatx4 oq[2] = {zero4, zero4}, od[2] = {zero4, zero4};
    #pragma unroll
    for (int ks = 0; ks < 4; ks++)
      #pragma unroll
      for (int nt = 0; nt < 2; nt++) {
        short8 bh_ = *(const short8*)&STh[nt * 16 + fr][fc8 + ks * 32];
        short8 bl_ = *(const short8*)&STl[nt * 16 + fr][fc8 + ks * 32];
        oq[nt] = __builtin_amdgcn_mfma_f32_16x16x32_bf16(Qr[ks], bh_, oq[nt], 0, 0, 0);
        oq[nt] = __builtin_amdgcn_mfma_f32_16x16x32_bf16(Qr[ks], bl_, oq[nt], 0, 0, 0);
      }
    #pragma unroll
    for (int ks = 0; ks < 2; ks++)
      #pragma unroll
      for (int nt = 0; nt < 2; nt++) {
        short8 bh_ = *(const short8*)&DTh[nt * 16 + fr][fc8 + ks * 32];
        short8 bl_ = *(const short8*)&DTl[nt * 16 + fr][fc8 + ks * 32];
        od[nt] = __builtin_amdgcn_mfma_f32_16x16x32_bf16(Mr[ks], bh_, od[nt], 0, 0, 0);
        od[nt] = __builtin_amdgcn_mfma_f32_16x16x32_bf16(Mr[ks], bl_, od[nt], 0, 0, 0);
      }
    #pragma unroll
    for (int nt = 0; nt < 2; nt++)
      #pragma unroll
      for (int r = 0; r < 4; r++) {
        int i = w16 + cr + r;
        cbase[(size_t)(tok0 + i) * VALD + nt * 16 + fr] = sQv[i] * oq[nt][r] + od[nt][r];
      }

    float eL = expf(sLgC[0]);
    #pragma unroll
    for (int mt = 0; mt < 2; mt++)
      #pragma unroll
      for (int nt = 0; nt < 2; nt++)
        #pragma unroll
        for (int r = 0; r < 4; r++)
          sacc[mt][nt][r] *= eL;
    #pragma unroll
    for (int ks = 0; ks < 2; ks++) {
      short8 afm[2];
      #pragma unroll
      for (int mt = 0; mt < 2; mt++) {
        short8 a;
        #pragma unroll
        for (int jj = 0; jj < 8; jj++) {
          int tk = fc8 + ks * 32 + jj;
          float kv = bf2f(Kt[tk][w32 + mt * 16 + fr]);
          a[jj] = (short)f2bf(kv * sKh[tk]);
        }
        afm[mt] = a;
      }
      #pragma unroll
      for (int mt = 0; mt < 2; mt++)
        #pragma unroll
        for (int nt = 0; nt < 2; nt++) {
          short8 bh_ = *(const short8*)&DTh[nt * 16 + fr][fc8 + ks * 32];
          short8 bl_ = *(const short8*)&DTl[nt * 16 + fr][fc8 + ks * 32];
          sacc[mt][nt] = __builtin_amdgcn_mfma_f32_16x16x32_bf16(afm[mt], bh_, sacc[mt][nt], 0, 0, 0);
          sacc[mt][nt] = __builtin_amdgcn_mfma_f32_16x16x32_bf16(afm[mt], bl_, sacc[mt][nt], 0, 0, 0);
        }
    }
    BAR();  // E
    #pragma unroll
    for (int mt = 0; mt < 2; mt++)
      #pragma unroll
      for (int nt = 0; nt < 2; nt++) {
        unsigned hv[4], lv[4];
        #pragma unroll
        for (int r = 0; r < 4; r++) {
          float sv = sacc[mt][nt][r];
          unsigned short hq = f2bf(sv);
          hv[r] = hq; lv[r] = f2bf(sv - bf2f(hq));
        }
        int v = nt * 16 + fr, k0 = w32 + mt * 16 + cr;
        *(uint2*)&STh[v][k0] = make_uint2(hv[0] | (hv[1] << 16), hv[2] | (hv[3] << 16));
        *(uint2*)&STl[v][k0] = make_uint2(lv[0] | (lv[1] << 16), lv[2] | (lv[3] << 16));
      }
  };

  KReg RA, RB;
  RA.gLg = RA.gB = RA.gLgC = 0.f;
  RB.gLg = RB.gB = RB.gLgC = 0.f;
  kpre(RA, 0);
  #pragma unroll 1
  for (int ch = 0; ch < NCHUNK; ch += 2) {
    body(RA, RB, ch);
    body(RB, RA, ch + 1);
  }
}

// ------------- RMSNorm(1+w) * silu(z) -> bf16 -------------
__global__ __launch_bounds__(256) void rmsnorm_silu(
    const float* __restrict__ core, const float* __restrict__ zbuf,
    const float* __restrict__ norm_w, ushort* __restrict__ out_bf) {
  int t = blockIdx.x;
  int tid = threadIdx.x;
  const float* row = core + (size_t)t * VALD;
  const float* zrow = zbuf + (size_t)t * VALD;
  ushort* orow = out_bf + (size_t)t * VALD;
  float vals[16];
  float ss = 0.f;
  #pragma unroll
  for (int i = 0; i < 16; i++) { float x = row[tid + i * 256]; vals[i] = x; ss += x * x; }
  #pragma unroll
  for (int off = 32; off >= 1; off >>= 1) ss += __shfl_xor(ss, off, 64);
  __shared__ float red[4];
  if ((tid & 63) == 0) red[tid >> 6] = ss;
  __syncthreads();
  float tot = red[0] + red[1] + red[2] + red[3];
  float scale = rsqrtf(tot * (1.f / VALD) + EPSF);
  #pragma unroll
  for (int i = 0; i < 16; i++) {
    int c = tid + i * 256;
    float z = zrow[c];
    float sz = z / (1.f + expf(-z));
    orow[c] = f2bf(vals[i] * scale * (1.f + norm_w[c]) * sz);
  }
}

extern "C" void kernel_launch(void* const* d_in, const int* in_sizes, int n_in,
                              void* d_out, int out_size, void* d_ws, size_t ws_size,
                              hipStream_t stream) {
  const float* x       = (const float*)d_in[0];
  const float* W_qkvz  = (const float*)d_in[1];
  const float* W_ba    = (const float*)d_in[2];
  const float* conv_w  = (const float*)d_in[3];
  const float* dt_bias = (const float*)d_in[4];
  const float* A_log   = (const float*)d_in[5];
  const float* norm_w  = (const float*)d_in[6];
  const float* W_out   = (const float*)d_in[7];
  float* out = (float*)d_out;

  // workspace layout (floats), total 84,410,368 fl = 337.6 MB
  float* ws = (float*)d_ws;
  float* A  = ws;                         // 33,554,432 fl
  float* Bp = A + (size_t)33554432;       // 33,554,432 fl
  float* Cp = Bp + (size_t)33554432;      // 16,777,216 fl
  float* ba = Cp + (size_t)16777216;      //    262,144 fl
  float* g2 = ba + (size_t)262144;        //    262,144 fl (float2[TOK*32])

  ushort* x_bf    = (ushort*)Cp;
  ushort* Wqkv_bf = (ushort*)Bp;
  float*  zb      = A;
  ushort* core_bf = (ushort*)(A + (size_t)16777216);
  ushort* Wz_bf   = (ushort*)(A + (size_t)25165824);
  ushort* Wo_bf   = (ushort*)Bp;
  float*  mix     = Bp;
  float*  core    = Cp;
  ushort* Tbuf    = (ushort*)(A + (size_t)16777216);
  ushort* Mbuf    = (ushort*)(A + (size_t)20971520);
  ushort* kq_bf   = (ushort*)(A + (size_t)25165824);
  float*  Lgbuf   = ba;

  // 1) casts for qkv projection
  cast_bf16<<<(TOK * HS / 4 + 255) / 256, 256, 0, stream>>>((const float4*)x, (ushort4*)x_bf, TOK * HS / 4);
  cast_bf16<<<(CONVD * HS / 4 + 255) / 256, 256, 0, stream>>>((const float4*)W_qkvz, (ushort4*)Wqkv_bf, CONVD * HS / 4);
  // 2) qkv projection (256^2 8-phase bf16 MFMA): [TOK, 8192]
  gemm256<<<dim3(CONVD / 256, TOK / 256), 512, 0, stream>>>(x_bf, Wqkv_bf, A, TOK, CONVD, HS);
  // 3) ba projection (fp32, tiny)
  gemm_nt<<<dim3(1, TOK / 64), 256, 0, stream>>>(x, W_ba, ba, TOK, 64, HS);
  // 4) conv + silu: A -> mix
  conv_silu<<<(int)(((size_t)TOK * CONVD) / 256), 256, 0, stream>>>(A, conv_w, mix);
  // 5) z projection
  cast_bf16<<<(VALD * HS / 4 + 255) / 256, 256, 0, stream>>>(
      (const float4*)(W_qkvz + (size_t)(2 * KEYD + VALD) * HS), (ushort4*)Wz_bf, VALD * HS / 4);
  gemm256<<<dim3(VALD / 256, TOK / 256), 512, 0, stream>>>(x_bf, Wz_bf, zb, TOK, VALD, HS);
  // 6) gates -> float2 {lg, beta}
  gates_kernel<<<TOK * NVH / 256, 256, 0, stream>>>(ba, A_log, dt_bias, (float2*)g2);
  // 7) l2 norm q,k -> bf16 kq buffer
  l2norm_qk<<<TOK * 32 / 4, 256, 0, stream>>>(mix, kq_bf);
  // 8) chunked delta-rule scan
  chunk_prep<<<NBATCH * NVH * NCHUNK, 64, 0, stream>>>(kq_bf, (const float2*)g2, Lgbuf, Tbuf, Mbuf);
  chunk_scan<<<NBATCH * NVH * 4, 256, 0, stream>>>(mix, kq_bf, (const float2*)g2, Lgbuf, Tbuf, Mbuf, core);
  // 9) rmsnorm * silu(z) -> bf16
  rmsnorm_silu<<<TOK, 256, 0, stream>>>(core, zb, norm_w, core_bf);
  // 10) output projection
  cast_bf16<<<(HS * VALD / 4 + 255) / 256, 256, 0, stream>>>((const float4*)W_out, (ushort4*)Wo_bf, HS * VALD / 4);
  gemm256<<<dim3(HS / 256, TOK / 256), 512, 0, stream>>>(core_bf, Wo_bf, out, TOK, HS, VALD);
}